// Round 13
// baseline (900.049 us; speedup 1.0000x reference)
//
#include <hip/hip_runtime.h>
#include <hip/hip_bf16.h>
#include <math.h>

#define NS 480   // n*s
#define NN 16
#define SS 30
#define CC 64
#define HHH 64
#define WW 22
#define PP 7
#define MAXH 22
#define CP 64
#define VV 17
#define DD 1536
#define OC 256
#define SILD 1408   // c*MAXH
#define NTOK 3360   // NS*PP
#define LDQ 776

// INSTRUMENTATION REPs (all bodies idempotent; remove next round)
#define PREP_REP 4
#define FC_REP   48
#define BN_REP   64
#define QKV_REP  32
#define ATTN_REP 16

typedef __bf16 bf16x8 __attribute__((ext_vector_type(8)));
typedef float f32x4 __attribute__((ext_vector_type(4)));
typedef short short8 __attribute__((ext_vector_type(8)));

__device__ __forceinline__ void gl_lds16(const void* g, void* l) {
    __builtin_amdgcn_global_load_lds(
        (const __attribute__((address_space(1))) void*)g,
        (__attribute__((address_space(3))) void*)l, 16, 0, 0);
}

__device__ __forceinline__ float bf2f(short s) {
    union { float f; unsigned u; } uu; uu.u = ((unsigned)(unsigned short)s) << 16; return uu.f;
}

// ============ K1: pool+gather + weight/pose prep ============
__global__ __launch_bounds__(256) void prep(const float* __restrict__ sil,
                                            const int* __restrict__ min_idx,
                                            const float* __restrict__ wqkv,
                                            const float* __restrict__ wproj,
                                            const float* __restrict__ fcbin,
                                            const float* __restrict__ pose,
                                            __hip_bfloat16* __restrict__ fuse,
                                            __hip_bfloat16* __restrict__ wqkv16,
                                            __hip_bfloat16* __restrict__ wproj16,
                                            __hip_bfloat16* __restrict__ fcbinT16) {
    __shared__ __align__(16) char smem[47552];
    int b = blockIdx.x, tid = threadIdx.x;
    #pragma unroll 1
    for (int rep = 0; rep < PREP_REP; rep++) {
    __syncthreads();
    if (b < 3840) {
        float* lds  = (float*)smem;
        float* hbuf = (float*)(smem + 45056);
        int*   mi_s = (int*)(smem + 47104);
        if (tid < 112) mi_s[tid] = min_idx[tid];
        long long base = (long long)b * 11264;
        int w = tid >> 6, lane = tid & 63;
        const char* gsrc = (const char*)(sil + base) + lane * 16;
        #pragma unroll
        for (int i = 0; i < 11; i++) {
            int ci = w * 11 + i;
            gl_lds16(gsrc + ci * 1024, (char*)smem + ci * 1024);
        }
        __syncthreads();
        #pragma unroll
        for (int rr = 0; rr < 2; rr++) {
            int r = tid + rr * 256;
            const float* row = lds + r * 22;
            float s = 0.f, m = -INFINITY;
            #pragma unroll
            for (int k = 0; k < WW; k++) { float v = row[k]; s += v; m = fmaxf(m, v); }
            hbuf[r] = s * (1.0f / WW) + m;
        }
        __syncthreads();
        int q0 = b * 8;
        for (int idx = tid; idx < 8 * PP * MAXH; idx += 256) {
            int hh = idx % MAXH;
            int t2 = idx / MAXH;
            int j = t2 % PP, qi = t2 / PP;
            int q = q0 + qi;
            int s_i = q % SS, t3 = q / SS;
            int c = t3 & 63, n = t3 >> 6;
            int mi = mi_s[j * NN + n];
            fuse[((long long)(j * NS + n * SS + s_i)) * DD + c * MAXH + hh] =
                __float2bfloat16(hbuf[qi * 64 + mi + hh]);
        }
        continue;
    }
    int b2 = b - 3840;
    if (b2 < 768)  { int g = b2 * 256 + tid; wqkv16[g] = __float2bfloat16(wqkv[g]); continue; }
    if (b2 < 1024) { int g = (b2 - 768) * 256 + tid; wproj16[g] = __float2bfloat16(wproj[g]); continue; }
    if (b2 < 1696) {
        float (*t)[65] = (float(*)[65])smem;
        int bb = b2 - 1024;
        int p = bb / 96, r2 = bb % 96, dt = r2 / 4, ot = r2 % 4;
        const float* s = fcbin + ((long long)p * DD + dt * 64) * OC + ot * 64;
        for (int i = tid; i < 64 * 64; i += 256) {
            int r = i >> 6, c = i & 63;
            t[r][c] = s[(long long)r * OC + c];
        }
        __syncthreads();
        __hip_bfloat16* d = fcbinT16 + ((long long)p * OC + ot * 64) * DD + dt * 64;
        for (int i = tid; i < 64 * 64; i += 256) {
            int r = i >> 6, c = i & 63;
            d[(long long)r * DD + c] = __float2bfloat16(t[c][r]);
        }
        continue;
    }
    int g = (b2 - 1696) * 256 + tid;
    int dd = g & 127;
    int t2 = g >> 7;
    int nsi = t2 % NS;
    int j = t2 / NS;
    int n = nsi / SS, s_i = nsi % SS;
    int cpi = dd >> 1, par = dd & 1;
    const float* pr = pose + (((long long)n * CP + cpi) * SS + s_i) * VV;
    float v;
    if (j == 0) {
        v = (par == 0) ? (pr[0] + pr[1] + pr[2]) * (1.f / 3.f)
                       : (pr[2] + pr[3] + pr[4]) * (1.f / 3.f);
    } else {
        v = pr[5 + (j - 1) * 2 + par];
    }
    v = (v > 0.f) ? v : 0.01f * v;
    fuse[(long long)(j * NS + nsi) * DD + SILD + dd] = __float2bfloat16(v);
    }
}

// ============ K2: fc MFMA GEMM (8 waves, K-split) + BN partials ============
__global__ __launch_bounds__(512) void gemm_fc(
    const __hip_bfloat16* __restrict__ Ain, const __hip_bfloat16* __restrict__ Bt,
    float* __restrict__ Cf, float* __restrict__ partial)
{
    const int M = 480, K = 1536, lda = 1536, ldc = 1792;
    const __hip_bfloat16* Ab = Ain + (long long)blockIdx.z * 480 * 1536;
    const __hip_bfloat16* Bq = Bt + (long long)blockIdx.z * 256 * 1536;
    float* C = Cf + (long long)blockIdx.z * 256;

    __shared__ short As[2][2][4096];
    __shared__ short Bs[2][2][4096];
    __shared__ float red[4][2][16][2];

    int tid = threadIdx.x, lane = tid & 63, w = tid >> 6;
    int kg = w >> 2, wq = w & 3;
    int wm = wq >> 1, wn = wq & 1;
    int row0 = blockIdx.x * 64, col0 = blockIdx.y * 64;
    int kbase = kg * 768;

    auto stage = [&](int buf, int k0) {
        int cc = lane & 7;
        #pragma unroll
        for (int i = 0; i < 2; i++) {
            int r = wq * 16 + i * 8 + (lane >> 3);
            int grow = row0 + r; if (grow >= M) grow = M - 1;
            long long kk = kbase + k0;
            const char* ga = (const char*)Ab + (((long long)grow * lda + kk) << 1) + ((cc ^ (r & 7)) << 4);
            gl_lds16(ga, (char*)&As[kg][buf][0] + (wq * 16 + i * 8) * 128);
            const char* gb = (const char*)Bq + (((long long)(col0 + r) * K + kk) << 1) + ((cc ^ (r & 7)) << 4);
            gl_lds16(gb, (char*)&Bs[kg][buf][0] + (wq * 16 + i * 8) * 128);
        }
    };

    #pragma unroll 1
    for (int rep = 0; rep < FC_REP; rep++) {
    __syncthreads();
    f32x4 acc[2][2] = {};
    stage(0, 0);
    __syncthreads();
    for (int t = 0; t < 12; t++) {
        int cur = t & 1;
        if (t + 1 < 12) stage(cur ^ 1, (t + 1) << 6);
        #pragma unroll
        for (int ks = 0; ks < 2; ks++) {
            bf16x8 af[2], bfv[2];
            #pragma unroll
            for (int f = 0; f < 2; f++) {
                int r = wm * 32 + f * 16 + (lane & 15);
                int ca = (ks * 4 + (lane >> 4)) ^ (r & 7);
                af[f] = *(const bf16x8*)((const char*)&As[kg][cur][0] + r * 128 + (ca << 4));
                int rb = wn * 32 + f * 16 + (lane & 15);
                int cb = (ks * 4 + (lane >> 4)) ^ (rb & 7);
                bfv[f] = *(const bf16x8*)((const char*)&Bs[kg][cur][0] + rb * 128 + (cb << 4));
            }
            #pragma unroll
            for (int fm = 0; fm < 2; fm++)
                #pragma unroll
                for (int fn = 0; fn < 2; fn++)
                    acc[fm][fn] = __builtin_amdgcn_mfma_f32_16x16x32_bf16(
                        af[fm], bfv[fn], acc[fm][fn], 0, 0, 0);
        }
        __syncthreads();
    }

    float* redC = (float*)&As[0][0][0];
    if (kg == 1) {
        #pragma unroll
        for (int fm = 0; fm < 2; fm++)
            #pragma unroll
            for (int fn = 0; fn < 2; fn++)
                #pragma unroll
                for (int r4 = 0; r4 < 4; r4++) {
                    int rl = wm * 32 + fm * 16 + (lane >> 4) * 4 + r4;
                    int cl = wn * 32 + fn * 16 + (lane & 15);
                    redC[rl * 64 + cl] = acc[fm][fn][r4];
                }
    }
    __syncthreads();

    if (kg == 0) {
        float s[2] = {0.f, 0.f}, s2[2] = {0.f, 0.f};
        #pragma unroll
        for (int fm = 0; fm < 2; fm++) {
            #pragma unroll
            for (int fn = 0; fn < 2; fn++) {
                #pragma unroll
                for (int r4 = 0; r4 < 4; r4++) {
                    int rl = wm * 32 + fm * 16 + (lane >> 4) * 4 + r4;
                    int cl = wn * 32 + fn * 16 + (lane & 15);
                    int grow = row0 + rl;
                    if (grow < M) {
                        float v = acc[fm][fn][r4] + redC[rl * 64 + cl];
                        C[(long long)grow * ldc + col0 + cl] = v;
                        s[fn] += v; s2[fn] += v * v;
                    }
                }
            }
        }
        #pragma unroll
        for (int off = 16; off < 64; off <<= 1) {
            s[0] += __shfl_xor(s[0], off);  s2[0] += __shfl_xor(s2[0], off);
            s[1] += __shfl_xor(s[1], off);  s2[1] += __shfl_xor(s2[1], off);
        }
        if (lane < 16) {
            red[wq][0][lane][0] = s[0]; red[wq][0][lane][1] = s2[0];
            red[wq][1][lane][0] = s[1]; red[wq][1][lane][1] = s2[1];
        }
    }
    __syncthreads();
    if (tid < 128) {
        int col = tid >> 1, which = tid & 1;
        int wn2 = (col >> 5) & 1, fn2 = (col >> 4) & 1, c16 = col & 15;
        float v = red[wn2][fn2][c16][which] + red[2 + wn2][fn2][c16][which];
        partial[((long long)(blockIdx.z * 8 + blockIdx.x) * 2 + which) * 256 + blockIdx.y * 64 + col] = v;
    }
    }
}

// ============ K3: BN final (1 block) ============
__global__ __launch_bounds__(256) void bnfinal(const float* __restrict__ partial,
                                               const float* __restrict__ gamma,
                                               const float* __restrict__ beta,
                                               float* __restrict__ ssbuf) {
    int t = threadIdx.x;
    #pragma unroll 1
    for (int rep = 0; rep < BN_REP; rep++) {
    float s = 0.f, s2 = 0.f;
    #pragma unroll 8
    for (int b = 0; b < 56; b++) { s += partial[b * 512 + t]; s2 += partial[b * 512 + 256 + t]; }
    float mu = s / (float)NTOK;
    float var = s2 / (float)NTOK - mu * mu;
    float rsig = rsqrtf(var + 1e-5f);
    float sc = gamma[t] * rsig;
    ssbuf[t] = sc;
    ssbuf[256 + t] = beta[t] - mu * sc;
    }
}

// ============ K4: qkv GEMM [3360x256]*[768x256]^T -> bf16, BN folded ============
__global__ __launch_bounds__(256) void gemm_qkv(
    const float* __restrict__ xraw, const __hip_bfloat16* __restrict__ Bt,
    const float* __restrict__ ssb, __hip_bfloat16* __restrict__ qkv16)
{
    const int M = 3360, K = 256;
    __shared__ short As[2][4096];
    __shared__ short Bs[2][4096];
    __shared__ float ssl[512];
    int tid = threadIdx.x, lane = tid & 63, w = tid >> 6;
    int wm = w >> 1, wn = w & 1;
    int row0 = blockIdx.x * 64, col0 = blockIdx.y * 64;

    for (int i = tid; i < 512; i += 256) ssl[i] = ssb[i];
    __syncthreads();

    auto stageB = [&](int buf, int k0) {
        int cc = lane & 7;
        #pragma unroll
        for (int i = 0; i < 2; i++) {
            int r = w * 16 + i * 8 + (lane >> 3);
            const char* gb = (const char*)Bt + (((long long)(col0 + r) * K + k0) << 1) + ((cc ^ (r & 7)) << 4);
            gl_lds16(gb, (char*)&Bs[buf][0] + (w * 16 + i * 8) * 128);
        }
    };
    auto stageA = [&](int buf, int k0) {
        #pragma unroll
        for (int i = 0; i < 2; i++) {
            int id = tid + i * 256;
            int r = id >> 3, c8 = id & 7;
            int grow = row0 + r; if (grow >= M) grow = M - 1;
            const float* src = xraw + (long long)grow * 256 + k0 + c8 * 8;
            float4 v0 = *(const float4*)src;
            float4 v1 = *(const float4*)(src + 4);
            int kb = k0 + c8 * 8;
            float vv[8] = {v0.x, v0.y, v0.z, v0.w, v1.x, v1.y, v1.z, v1.w};
            short8 o;
            #pragma unroll
            for (int j = 0; j < 8; j++) {
                float tv = vv[j] * ssl[kb + j] + ssl[256 + kb + j];
                union { __hip_bfloat16 h; short s; } u; u.h = __float2bfloat16(tv);
                o[j] = u.s;
            }
            *(short8*)((char*)&As[buf][0] + r * 128 + ((c8 ^ (r & 7)) << 4)) = o;
        }
    };

    #pragma unroll 1
    for (int rep = 0; rep < QKV_REP; rep++) {
    __syncthreads();
    f32x4 acc[2][2] = {};
    stageA(0, 0); stageB(0, 0);
    __syncthreads();
    for (int t = 0; t < 4; t++) {
        int cur = t & 1;
        if (t + 1 < 4) { stageA(cur ^ 1, (t + 1) << 6); stageB(cur ^ 1, (t + 1) << 6); }
        #pragma unroll
        for (int ks = 0; ks < 2; ks++) {
            bf16x8 af[2], bfv[2];
            #pragma unroll
            for (int f = 0; f < 2; f++) {
                int r = wm * 32 + f * 16 + (lane & 15);
                int ca = (ks * 4 + (lane >> 4)) ^ (r & 7);
                af[f] = *(const bf16x8*)((const char*)&As[cur][0] + r * 128 + (ca << 4));
                int rb = wn * 32 + f * 16 + (lane & 15);
                int cb = (ks * 4 + (lane >> 4)) ^ (rb & 7);
                bfv[f] = *(const bf16x8*)((const char*)&Bs[cur][0] + rb * 128 + (cb << 4));
            }
            #pragma unroll
            for (int fm = 0; fm < 2; fm++)
                #pragma unroll
                for (int fn = 0; fn < 2; fn++)
                    acc[fm][fn] = __builtin_amdgcn_mfma_f32_16x16x32_bf16(
                        af[fm], bfv[fn], acc[fm][fn], 0, 0, 0);
        }
        __syncthreads();
    }
    #pragma unroll
    for (int fm = 0; fm < 2; fm++)
        #pragma unroll
        for (int fn = 0; fn < 2; fn++)
            #pragma unroll
            for (int r4 = 0; r4 < 4; r4++) {
                int grow = row0 + wm * 32 + fm * 16 + (lane >> 4) * 4 + r4;
                int gcol = col0 + wn * 32 + fn * 16 + (lane & 15);
                if (grow < M)
                    qkv16[(long long)grow * 768 + gcol] = __float2bfloat16(acc[fm][fn][r4]);
            }
    }
}

// ============ K5: attention + proj + residual + transposed out ============
__global__ __launch_bounds__(256) void attnproj(const __hip_bfloat16* __restrict__ qkv16,
                                                const __hip_bfloat16* __restrict__ wproj16,
                                                const float* __restrict__ xraw,
                                                const float* __restrict__ ssb,
                                                float* __restrict__ outp) {
    __shared__ __align__(16) char sm[33728];
    float* qkvs = (float*)sm;
    float* Ct   = (float*)sm;
    short* ao_s = (short*)(sm + 21728);
    float (*as_)[49] = (float(*)[49])(sm + 29920);
    float* ssl  = (float*)(sm + 31680);

    int tid = threadIdx.x, lane = tid & 63, w = tid >> 6;
    int token0 = blockIdx.x * 7;

    for (int i = tid; i < 512; i += 256) ssl[i] = ssb[i];

    #pragma unroll 1
    for (int rep = 0; rep < ATTN_REP; rep++) {
    __syncthreads();
    const short* src = (const short*)qkv16 + (long long)token0 * 768;
    for (int c = tid; c < 672; c += 256) {
        int r = c / 96, c8 = (c % 96) * 8;
        short8 v = *(const short8*)(src + r * 768 + c8);
        float4 f0, f1;
        f0.x = bf2f(v[0]); f0.y = bf2f(v[1]); f0.z = bf2f(v[2]); f0.w = bf2f(v[3]);
        f1.x = bf2f(v[4]); f1.y = bf2f(v[5]); f1.z = bf2f(v[6]); f1.w = bf2f(v[7]);
        *(float4*)&qkvs[r * LDQ + c8] = f0;
        *(float4*)&qkvs[r * LDQ + c8 + 4] = f1;
    }
    __syncthreads();

    for (int t = tid; t < 392; t += 256) {
        int h = t / 49, ij = t % 49, i = ij / 7, j = ij % 7;
        const float* qp = qkvs + i * LDQ + h * 32;
        const float* kp = qkvs + j * LDQ + 256 + h * 32;
        float acc = 0.f;
        #pragma unroll
        for (int d = 0; d < 32; d++) acc += qp[d] * kp[d];
        as_[h][ij] = acc * 0.17677669529663689f;
    }
    __syncthreads();
    if (tid < 49) {
        float m = -INFINITY;
        #pragma unroll
        for (int h = 0; h < 8; h++) m = fmaxf(m, as_[h][tid]);
        float e[8], sum = 0.f;
        #pragma unroll
        for (int h = 0; h < 8; h++) { e[h] = __expf(as_[h][tid] - m); sum += e[h]; }
        float inv = 1.f / sum;
        #pragma unroll
        for (int h = 0; h < 8; h++) as_[h][tid] = e[h] * inv;
    }
    __syncthreads();
    #pragma unroll
    for (int tl = 0; tl < 16; tl++) {
        int col = tid;
        float acc = 0.f;
        if (tl < 7) {
            int h = col >> 5;
            const float* ap = &as_[h][tl * 7];
            const float* vp = qkvs + 512 + col;
            #pragma unroll
            for (int j = 0; j < 7; j++) acc += ap[j] * vp[j * LDQ];
        }
        int c16 = col >> 3;
        union { __hip_bfloat16 h2; short s2; } u; u.h2 = __float2bfloat16(acc);
        ao_s[tl * 256 + ((c16 ^ (tl & 7)) << 3) + (col & 7)] = u.s2;
    }
    __syncthreads();
    f32x4 pacc[4] = {};
    int n0 = w * 64;
    #pragma unroll
    for (int k0 = 0; k0 < 256; k0 += 32) {
        int rowa = lane & 15;
        int kk = k0 + (lane >> 4) * 8;
        int c16a = kk >> 3;
        bf16x8 af = *(const bf16x8*)(const void*)&ao_s[rowa * 256 + ((c16a ^ (rowa & 7)) << 3)];
        #pragma unroll
        for (int fn = 0; fn < 4; fn++) {
            int n = n0 + fn * 16 + (lane & 15);
            bf16x8 bfv = *(const bf16x8*)(const void*)((const short*)wproj16 + n * 256 + kk);
            pacc[fn] = __builtin_amdgcn_mfma_f32_16x16x32_bf16(af, bfv, pacc[fn], 0, 0, 0);
        }
    }
    __syncthreads();
    #pragma unroll
    for (int fn = 0; fn < 4; fn++)
        #pragma unroll
        for (int r4 = 0; r4 < 4; r4++) {
            int tk = (lane >> 4) * 4 + r4;
            if (tk < 7) {
                int o = n0 + fn * 16 + (lane & 15);
                Ct[o * 9 + tk] = pacc[fn][r4];
            }
        }
    __syncthreads();
    int o = tid;
    int n = token0 / 210, rem0 = token0 % 210;
    float* op = outp + ((long long)(n * 256 + o)) * 210 + rem0;
    float sc = ssl[o], sh = ssl[256 + o];
    #pragma unroll
    for (int tk = 0; tk < 7; tk++) {
        op[tk] = Ct[o * 9 + tk] + xraw[(long long)(token0 + tk) * 256 + o] * sc + sh;
    }
    }
}

extern "C" void kernel_launch(void* const* d_in, const int* in_sizes, int n_in,
                              void* d_out, int out_size, void* d_ws, size_t ws_size,
                              hipStream_t stream) {
    const float* sil   = (const float*)d_in[0];
    const float* pose  = (const float*)d_in[1];
    const float* fcbin = (const float*)d_in[2];
    const float* gamma = (const float*)d_in[3];
    const float* beta  = (const float*)d_in[4];
    const float* wqkv  = (const float*)d_in[5];
    const float* wproj = (const float*)d_in[6];
    const int*   minidx= (const int*)d_in[7];
    float* out = (float*)d_out;

    float* ws = (float*)d_ws;
    __hip_bfloat16* fuse16   = (__hip_bfloat16*)ws;             // 5,160,960 bf16
    float* xraw    = ws + 2580480;                              // 860,160 f32
    float* partial = ws + 3440640;                              // 28,672
    float* ssbuf   = ws + 3469312;                              // 512
    __hip_bfloat16* wqkv16   = (__hip_bfloat16*)(ws + 3469824); // 196,608 bf16
    __hip_bfloat16* wproj16  = (__hip_bfloat16*)(ws + 3568128); // 65,536 bf16
    __hip_bfloat16* fcbinT16 = (__hip_bfloat16*)(ws + 3600896); // 2,752,512 bf16
    __hip_bfloat16* qkv16    = (__hip_bfloat16*)(ws + 4977152); // 2,580,480 bf16

    prep<<<7216, 256, 0, stream>>>(sil, minidx, wqkv, wproj, fcbin, pose,
                                   fuse16, wqkv16, wproj16, fcbinT16);
    gemm_fc<<<dim3(8, 4, 7), 512, 0, stream>>>(fuse16, fcbinT16, xraw, partial);
    bnfinal<<<1, 256, 0, stream>>>(partial, gamma, beta, ssbuf);
    gemm_qkv<<<dim3(53, 12), 256, 0, stream>>>(xraw, wqkv16, ssbuf, qkv16);
    attnproj<<<480, 256, 0, stream>>>(qkv16, wproj16, xraw, ssbuf, out);
}

// Round 14
// 86.936 us; speedup vs baseline: 10.3530x; 10.3530x over previous
//
#include <hip/hip_runtime.h>
#include <hip/hip_bf16.h>
#include <math.h>

#define NS 480   // n*s
#define NN 16
#define SS 30
#define CC 64
#define HHH 64
#define WW 22
#define PP 7
#define MAXH 22
#define CP 64
#define VV 17
#define DD 1536
#define OC 256
#define SILD 1408   // c*MAXH
#define NTOK 3360   // NS*PP
#define LDQ 776
#define FCGROUPS 105   // 15 M-tiles x 7 parts

typedef __bf16 bf16x8 __attribute__((ext_vector_type(8)));
typedef float f32x4 __attribute__((ext_vector_type(4)));
typedef short short8 __attribute__((ext_vector_type(8)));

__device__ __forceinline__ void gl_lds16(const void* g, void* l) {
    __builtin_amdgcn_global_load_lds(
        (const __attribute__((address_space(1))) void*)g,
        (__attribute__((address_space(3))) void*)l, 16, 0, 0);
}

__device__ __forceinline__ float bf2f(short s) {
    union { float f; unsigned u; } uu; uu.u = ((unsigned)(unsigned short)s) << 16; return uu.f;
}

// ============ K1: pool+gather (8 triples/block, gl_lds streaming) + weight/pose prep ============
__global__ __launch_bounds__(256) void prep(const float* __restrict__ sil,
                                            const int* __restrict__ min_idx,
                                            const float* __restrict__ wqkv,
                                            const float* __restrict__ wproj,
                                            const float* __restrict__ fcbin,
                                            const float* __restrict__ pose,
                                            __hip_bfloat16* __restrict__ fuse,
                                            __hip_bfloat16* __restrict__ wqkv16,
                                            __hip_bfloat16* __restrict__ wproj16,
                                            __hip_bfloat16* __restrict__ fcbinT16) {
    __shared__ __align__(16) char smem[47552];
    int b = blockIdx.x, tid = threadIdx.x;
    if (b < 3840) {
        float* lds  = (float*)smem;
        float* hbuf = (float*)(smem + 45056);
        int*   mi_s = (int*)(smem + 47104);
        if (tid < 112) mi_s[tid] = min_idx[tid];
        long long base = (long long)b * 11264;
        int w = tid >> 6, lane = tid & 63;
        const char* gsrc = (const char*)(sil + base) + lane * 16;
        #pragma unroll
        for (int i = 0; i < 11; i++) {
            int ci = w * 11 + i;
            gl_lds16(gsrc + ci * 1024, (char*)smem + ci * 1024);
        }
        __syncthreads();
        #pragma unroll
        for (int rr = 0; rr < 2; rr++) {
            int r = tid + rr * 256;
            const float* row = lds + r * 22;
            float s = 0.f, m = -INFINITY;
            #pragma unroll
            for (int k = 0; k < WW; k++) { float v = row[k]; s += v; m = fmaxf(m, v); }
            hbuf[r] = s * (1.0f / WW) + m;
        }
        __syncthreads();
        int q0 = b * 8;
        for (int idx = tid; idx < 8 * PP * MAXH; idx += 256) {
            int hh = idx % MAXH;
            int t2 = idx / MAXH;
            int j = t2 % PP, qi = t2 / PP;
            int q = q0 + qi;
            int s_i = q % SS, t3 = q / SS;
            int c = t3 & 63, n = t3 >> 6;
            int mi = mi_s[j * NN + n];
            fuse[((long long)(j * NS + n * SS + s_i)) * DD + c * MAXH + hh] =
                __float2bfloat16(hbuf[qi * 64 + mi + hh]);
        }
        return;
    }
    b -= 3840;
    if (b < 768)  { int g = b * 256 + tid; wqkv16[g] = __float2bfloat16(wqkv[g]); return; }
    if (b < 1024) { int g = (b - 768) * 256 + tid; wproj16[g] = __float2bfloat16(wproj[g]); return; }
    if (b < 1696) {
        float (*t)[65] = (float(*)[65])smem;
        int bb = b - 1024;
        int p = bb / 96, r2 = bb % 96, dt = r2 / 4, ot = r2 % 4;
        const float* s = fcbin + ((long long)p * DD + dt * 64) * OC + ot * 64;
        for (int i = tid; i < 64 * 64; i += 256) {
            int r = i >> 6, c = i & 63;
            t[r][c] = s[(long long)r * OC + c];
        }
        __syncthreads();
        __hip_bfloat16* d = fcbinT16 + ((long long)p * OC + ot * 64) * DD + dt * 64;
        for (int i = tid; i < 64 * 64; i += 256) {
            int r = i >> 6, c = i & 63;
            d[(long long)r * DD + c] = __float2bfloat16(t[c][r]);
        }
        return;
    }
    int g = (b - 1696) * 256 + tid;
    int dd = g & 127;
    int t2 = g >> 7;
    int nsi = t2 % NS;
    int j = t2 / NS;
    int n = nsi / SS, s_i = nsi % SS;
    int cpi = dd >> 1, par = dd & 1;
    const float* pr = pose + (((long long)n * CP + cpi) * SS + s_i) * VV;
    float v;
    if (j == 0) {
        v = (par == 0) ? (pr[0] + pr[1] + pr[2]) * (1.f / 3.f)
                       : (pr[2] + pr[3] + pr[4]) * (1.f / 3.f);
    } else {
        v = pr[5 + (j - 1) * 2 + par];
    }
    v = (v > 0.f) ? v : 0.01f * v;
    fuse[(long long)(j * NS + nsi) * DD + SILD + dd] = __float2bfloat16(v);
}

// ============ K2: fc MFMA GEMM, 32x64 tiles (420 blocks), 8 waves K-split, + BN partials ============
__global__ __launch_bounds__(512) void gemm_fc(
    const __hip_bfloat16* __restrict__ Ain, const __hip_bfloat16* __restrict__ Bt,
    float* __restrict__ Cf, float* __restrict__ partial)
{
    const int K = 1536, lda = 1536, ldc = 1792;
    const __hip_bfloat16* Ab = Ain + (long long)blockIdx.z * 480 * 1536;
    const __hip_bfloat16* Bq = Bt + (long long)blockIdx.z * 256 * 1536;
    float* C = Cf + (long long)blockIdx.z * 256;

    __shared__ short As[2][2][2048];      // [kg][buf][32*64]
    __shared__ short Bs[2][2][4096];      // [kg][buf][64*64]
    __shared__ float red[4][16][2];

    int tid = threadIdx.x, lane = tid & 63, w = tid >> 6;   // w: 0..7
    int kg = w >> 2, wq = w & 3;
    int row0 = blockIdx.x * 32, col0 = blockIdx.y * 64;
    int kbase = kg * 768;                 // each group: 12 K-steps of 64
    int ltid = tid & 255;

    f32x4 acc[2] = {};

    auto stage = [&](int buf, int k0) {   // k0 relative to kbase; 256 threads of this kg
        long long kk = kbase + k0;
        {   // A: 32 rows x 8 chunks = 256
            int r = ltid >> 3, c = ltid & 7;
            const char* ga = (const char*)Ab + (((long long)(row0 + r) * lda + kk) << 1) + ((c ^ (r & 7)) << 4);
            gl_lds16(ga, (char*)&As[kg][buf][0] + ltid * 16);
        }
        #pragma unroll
        for (int i = 0; i < 2; i++) {     // B: 64 rows x 8 chunks = 512
            int idx = ltid + i * 256;
            int r = idx >> 3, c = idx & 7;
            const char* gb = (const char*)Bq + (((long long)(col0 + r) * K + kk) << 1) + ((c ^ (r & 7)) << 4);
            gl_lds16(gb, (char*)&Bs[kg][buf][0] + idx * 16);
        }
    };

    stage(0, 0);
    __syncthreads();
    for (int t = 0; t < 12; t++) {
        int cur = t & 1;
        if (t + 1 < 12) stage(cur ^ 1, (t + 1) << 6);
        #pragma unroll
        for (int ks = 0; ks < 2; ks++) {
            bf16x8 af[2], bfv;
            #pragma unroll
            for (int f = 0; f < 2; f++) {
                int r = f * 16 + (lane & 15);
                int ca = (ks * 4 + (lane >> 4)) ^ (r & 7);
                af[f] = *(const bf16x8*)((const char*)&As[kg][cur][0] + r * 128 + (ca << 4));
            }
            int rb = wq * 16 + (lane & 15);
            int cb = (ks * 4 + (lane >> 4)) ^ (rb & 7);
            bfv = *(const bf16x8*)((const char*)&Bs[kg][cur][0] + rb * 128 + (cb << 4));
            acc[0] = __builtin_amdgcn_mfma_f32_16x16x32_bf16(af[0], bfv, acc[0], 0, 0, 0);
            acc[1] = __builtin_amdgcn_mfma_f32_16x16x32_bf16(af[1], bfv, acc[1], 0, 0, 0);
        }
        __syncthreads();
    }

    // cross-group reduce: kg1 -> LDS (reuse As space: 32*64 f32 = 8 KB), kg0 adds
    float* redC = (float*)&As[0][0][0];
    if (kg == 1) {
        #pragma unroll
        for (int f = 0; f < 2; f++)
            #pragma unroll
            for (int r4 = 0; r4 < 4; r4++) {
                int rl = f * 16 + (lane >> 4) * 4 + r4;
                int cl = wq * 16 + (lane & 15);
                redC[rl * 64 + cl] = acc[f][r4];
            }
    }
    __syncthreads();

    if (kg == 0) {
        float s = 0.f, s2 = 0.f;
        #pragma unroll
        for (int f = 0; f < 2; f++)
            #pragma unroll
            for (int r4 = 0; r4 < 4; r4++) {
                int rl = f * 16 + (lane >> 4) * 4 + r4;
                int cl = wq * 16 + (lane & 15);
                float v = acc[f][r4] + redC[rl * 64 + cl];
                C[(long long)(row0 + rl) * ldc + col0 + cl] = v;
                s += v; s2 += v * v;
            }
        s  += __shfl_xor(s, 16);  s2 += __shfl_xor(s2, 16);
        s  += __shfl_xor(s, 32);  s2 += __shfl_xor(s2, 32);
        if (lane < 16) { red[wq][lane][0] = s; red[wq][lane][1] = s2; }
    }
    __syncthreads();
    if (tid < 128) {
        int col = tid >> 1, which = tid & 1;
        float v = red[col >> 4][col & 15][which];
        int group = blockIdx.z * 15 + blockIdx.x;
        partial[((long long)group * 2 + which) * 256 + blockIdx.y * 64 + col] = v;
    }
}

// ============ K3: BN final (1 block) ============
__global__ __launch_bounds__(256) void bnfinal(const float* __restrict__ partial,
                                               const float* __restrict__ gamma,
                                               const float* __restrict__ beta,
                                               float* __restrict__ ssbuf) {
    int t = threadIdx.x;
    float s = 0.f, s2 = 0.f;
    #pragma unroll 8
    for (int b = 0; b < FCGROUPS; b++) { s += partial[b * 512 + t]; s2 += partial[b * 512 + 256 + t]; }
    float mu = s / (float)NTOK;
    float var = s2 / (float)NTOK - mu * mu;
    float rsig = rsqrtf(var + 1e-5f);
    float sc = gamma[t] * rsig;
    ssbuf[t] = sc;
    ssbuf[256 + t] = beta[t] - mu * sc;
}

// ============ K4: qkv GEMM [3360x256]*[768x256]^T -> bf16, BN folded ============
__global__ __launch_bounds__(256) void gemm_qkv(
    const float* __restrict__ xraw, const __hip_bfloat16* __restrict__ Bt,
    const float* __restrict__ ssb, __hip_bfloat16* __restrict__ qkv16)
{
    const int M = 3360, K = 256;
    __shared__ short As[2][4096];
    __shared__ short Bs[2][4096];
    __shared__ float ssl[512];
    int tid = threadIdx.x, lane = tid & 63, w = tid >> 6;
    int wm = w >> 1, wn = w & 1;
    int row0 = blockIdx.x * 64, col0 = blockIdx.y * 64;

    for (int i = tid; i < 512; i += 256) ssl[i] = ssb[i];
    __syncthreads();

    f32x4 acc[2][2] = {};

    auto stageB = [&](int buf, int k0) {
        int cc = lane & 7;
        #pragma unroll
        for (int i = 0; i < 2; i++) {
            int r = w * 16 + i * 8 + (lane >> 3);
            const char* gb = (const char*)Bt + (((long long)(col0 + r) * K + k0) << 1) + ((cc ^ (r & 7)) << 4);
            gl_lds16(gb, (char*)&Bs[buf][0] + (w * 16 + i * 8) * 128);
        }
    };
    auto stageA = [&](int buf, int k0) {
        #pragma unroll
        for (int i = 0; i < 2; i++) {
            int id = tid + i * 256;
            int r = id >> 3, c8 = id & 7;
            int grow = row0 + r; if (grow >= M) grow = M - 1;
            const float* src = xraw + (long long)grow * 256 + k0 + c8 * 8;
            float4 v0 = *(const float4*)src;
            float4 v1 = *(const float4*)(src + 4);
            int kb = k0 + c8 * 8;
            float vv[8] = {v0.x, v0.y, v0.z, v0.w, v1.x, v1.y, v1.z, v1.w};
            short8 o;
            #pragma unroll
            for (int j = 0; j < 8; j++) {
                float tv = vv[j] * ssl[kb + j] + ssl[256 + kb + j];
                union { __hip_bfloat16 h; short s; } u; u.h = __float2bfloat16(tv);
                o[j] = u.s;
            }
            *(short8*)((char*)&As[buf][0] + r * 128 + ((c8 ^ (r & 7)) << 4)) = o;
        }
    };

    stageA(0, 0); stageB(0, 0);
    __syncthreads();
    for (int t = 0; t < 4; t++) {
        int cur = t & 1;
        if (t + 1 < 4) { stageA(cur ^ 1, (t + 1) << 6); stageB(cur ^ 1, (t + 1) << 6); }
        #pragma unroll
        for (int ks = 0; ks < 2; ks++) {
            bf16x8 af[2], bfv[2];
            #pragma unroll
            for (int f = 0; f < 2; f++) {
                int r = wm * 32 + f * 16 + (lane & 15);
                int ca = (ks * 4 + (lane >> 4)) ^ (r & 7);
                af[f] = *(const bf16x8*)((const char*)&As[cur][0] + r * 128 + (ca << 4));
                int rb = wn * 32 + f * 16 + (lane & 15);
                int cb = (ks * 4 + (lane >> 4)) ^ (rb & 7);
                bfv[f] = *(const bf16x8*)((const char*)&Bs[cur][0] + rb * 128 + (cb << 4));
            }
            #pragma unroll
            for (int fm = 0; fm < 2; fm++)
                #pragma unroll
                for (int fn = 0; fn < 2; fn++)
                    acc[fm][fn] = __builtin_amdgcn_mfma_f32_16x16x32_bf16(
                        af[fm], bfv[fn], acc[fm][fn], 0, 0, 0);
        }
        __syncthreads();
    }
    #pragma unroll
    for (int fm = 0; fm < 2; fm++)
        #pragma unroll
        for (int fn = 0; fn < 2; fn++)
            #pragma unroll
            for (int r4 = 0; r4 < 4; r4++) {
                int grow = row0 + wm * 32 + fm * 16 + (lane >> 4) * 4 + r4;
                int gcol = col0 + wn * 32 + fn * 16 + (lane & 15);
                if (grow < M)
                    qkv16[(long long)grow * 768 + gcol] = __float2bfloat16(acc[fm][fn][r4]);
            }
}

// ============ K5: attention + proj + residual + transposed out (480 blocks x 7 tokens) ============
__global__ __launch_bounds__(256) void attnproj(const __hip_bfloat16* __restrict__ qkv16,
                                                const __hip_bfloat16* __restrict__ wproj16,
                                                const float* __restrict__ xraw,
                                                const float* __restrict__ ssb,
                                                float* __restrict__ outp) {
    __shared__ __align__(16) char sm[33728];
    float* qkvs = (float*)sm;
    float* Ct   = (float*)sm;
    short* ao_s = (short*)(sm + 21728);
    float (*as_)[49] = (float(*)[49])(sm + 29920);
    float* ssl  = (float*)(sm + 31680);

    int tid = threadIdx.x, lane = tid & 63, w = tid >> 6;
    int token0 = blockIdx.x * 7;

    for (int i = tid; i < 512; i += 256) ssl[i] = ssb[i];

    const short* src = (const short*)qkv16 + (long long)token0 * 768;
    for (int c = tid; c < 672; c += 256) {
        int r = c / 96, c8 = (c % 96) * 8;
        short8 v = *(const short8*)(src + r * 768 + c8);
        float4 f0, f1;
        f0.x = bf2f(v[0]); f0.y = bf2f(v[1]); f0.z = bf2f(v[2]); f0.w = bf2f(v[3]);
        f1.x = bf2f(v[4]); f1.y = bf2f(v[5]); f1.z = bf2f(v[6]); f1.w = bf2f(v[7]);
        *(float4*)&qkvs[r * LDQ + c8] = f0;
        *(float4*)&qkvs[r * LDQ + c8 + 4] = f1;
    }
    __syncthreads();

    for (int t = tid; t < 392; t += 256) {
        int h = t / 49, ij = t % 49, i = ij / 7, j = ij % 7;
        const float* qp = qkvs + i * LDQ + h * 32;
        const float* kp = qkvs + j * LDQ + 256 + h * 32;
        float acc = 0.f;
        #pragma unroll
        for (int d = 0; d < 32; d++) acc += qp[d] * kp[d];
        as_[h][ij] = acc * 0.17677669529663689f;
    }
    __syncthreads();
    if (tid < 49) {
        float m = -INFINITY;
        #pragma unroll
        for (int h = 0; h < 8; h++) m = fmaxf(m, as_[h][tid]);
        float e[8], sum = 0.f;
        #pragma unroll
        for (int h = 0; h < 8; h++) { e[h] = __expf(as_[h][tid] - m); sum += e[h]; }
        float inv = 1.f / sum;
        #pragma unroll
        for (int h = 0; h < 8; h++) as_[h][tid] = e[h] * inv;
    }
    __syncthreads();
    #pragma unroll
    for (int tl = 0; tl < 16; tl++) {
        int col = tid;
        float acc = 0.f;
        if (tl < 7) {
            int h = col >> 5;
            const float* ap = &as_[h][tl * 7];
            const float* vp = qkvs + 512 + col;
            #pragma unroll
            for (int j = 0; j < 7; j++) acc += ap[j] * vp[j * LDQ];
        }
        int c16 = col >> 3;
        union { __hip_bfloat16 h2; short s2; } u; u.h2 = __float2bfloat16(acc);
        ao_s[tl * 256 + ((c16 ^ (tl & 7)) << 3) + (col & 7)] = u.s2;
    }
    __syncthreads();
    f32x4 pacc[4] = {};
    int n0 = w * 64;
    #pragma unroll
    for (int k0 = 0; k0 < 256; k0 += 32) {
        int rowa = lane & 15;
        int kk = k0 + (lane >> 4) * 8;
        int c16a = kk >> 3;
        bf16x8 af = *(const bf16x8*)(const void*)&ao_s[rowa * 256 + ((c16a ^ (rowa & 7)) << 3)];
        #pragma unroll
        for (int fn = 0; fn < 4; fn++) {
            int n = n0 + fn * 16 + (lane & 15);
            bf16x8 bfv = *(const bf16x8*)(const void*)((const short*)wproj16 + n * 256 + kk);
            pacc[fn] = __builtin_amdgcn_mfma_f32_16x16x32_bf16(af, bfv, pacc[fn], 0, 0, 0);
        }
    }
    __syncthreads();
    #pragma unroll
    for (int fn = 0; fn < 4; fn++)
        #pragma unroll
        for (int r4 = 0; r4 < 4; r4++) {
            int tk = (lane >> 4) * 4 + r4;
            if (tk < 7) {
                int o = n0 + fn * 16 + (lane & 15);
                Ct[o * 9 + tk] = pacc[fn][r4];
            }
        }
    __syncthreads();
    int o = tid;
    int n = token0 / 210, rem0 = token0 % 210;
    float* op = outp + ((long long)(n * 256 + o)) * 210 + rem0;
    float sc = ssl[o], sh = ssl[256 + o];
    #pragma unroll
    for (int tk = 0; tk < 7; tk++) {
        op[tk] = Ct[o * 9 + tk] + xraw[(long long)(token0 + tk) * 256 + o] * sc + sh;
    }
}

extern "C" void kernel_launch(void* const* d_in, const int* in_sizes, int n_in,
                              void* d_out, int out_size, void* d_ws, size_t ws_size,
                              hipStream_t stream) {
    const float* sil   = (const float*)d_in[0];
    const float* pose  = (const float*)d_in[1];
    const float* fcbin = (const float*)d_in[2];
    const float* gamma = (const float*)d_in[3];
    const float* beta  = (const float*)d_in[4];
    const float* wqkv  = (const float*)d_in[5];
    const float* wproj = (const float*)d_in[6];
    const int*   minidx= (const int*)d_in[7];
    float* out = (float*)d_out;

    float* ws = (float*)d_ws;
    __hip_bfloat16* fuse16   = (__hip_bfloat16*)ws;             // 5,160,960 bf16
    float* xraw    = ws + 2580480;                              // 860,160 f32 (ldc=1792 view)
    float* partial = ws + 3440640;                              // 53,760 (105 groups x 512)
    float* ssbuf   = ws + 3494400;                              // 512
    __hip_bfloat16* wqkv16   = (__hip_bfloat16*)(ws + 3494912); // 196,608 bf16
    __hip_bfloat16* wproj16  = (__hip_bfloat16*)(ws + 3593216); // 65,536 bf16
    __hip_bfloat16* fcbinT16 = (__hip_bfloat16*)(ws + 3625984); // 2,752,512 bf16
    __hip_bfloat16* qkv16    = (__hip_bfloat16*)(ws + 5002240); // 2,580,480 bf16

    prep<<<7216, 256, 0, stream>>>(sil, minidx, wqkv, wproj, fcbin, pose,
                                   fuse16, wqkv16, wproj16, fcbinT16);
    gemm_fc<<<dim3(15, 4, 7), 512, 0, stream>>>(fuse16, fcbinT16, xraw, partial);
    bnfinal<<<1, 256, 0, stream>>>(partial, gamma, beta, ssbuf);
    gemm_qkv<<<dim3(53, 12), 256, 0, stream>>>(xraw, wqkv16, ssbuf, qkv16);
    attnproj<<<480, 256, 0, stream>>>(qkv16, wproj16, xraw, ssbuf, out);
}

// Round 15
// 78.709 us; speedup vs baseline: 11.4351x; 1.1045x over previous
//
#include <hip/hip_runtime.h>
#include <hip/hip_bf16.h>
#include <math.h>

#define NS 480   // n*s
#define NN 16
#define SS 30
#define CC 64
#define HHH 64
#define WW 22
#define PP 7
#define MAXH 22
#define CP 64
#define VV 17
#define DD 1536
#define OC 256
#define SILD 1408   // c*MAXH
#define NTOK 3360   // NS*PP
#define LDQ 776

typedef __bf16 bf16x8 __attribute__((ext_vector_type(8)));
typedef float f32x4 __attribute__((ext_vector_type(4)));
typedef short short8 __attribute__((ext_vector_type(8)));

__device__ __forceinline__ void gl_lds16(const void* g, void* l) {
    __builtin_amdgcn_global_load_lds(
        (const __attribute__((address_space(1))) void*)g,
        (__attribute__((address_space(3))) void*)l, 16, 0, 0);
}

__device__ __forceinline__ float bf2f(short s) {
    union { float f; unsigned u; } uu; uu.u = ((unsigned)(unsigned short)s) << 16; return uu.f;
}

// ============ K1: pool+gather (8 triples/block, gl_lds streaming) + weight/pose prep ============
__global__ __launch_bounds__(256) void prep(const float* __restrict__ sil,
                                            const int* __restrict__ min_idx,
                                            const float* __restrict__ wqkv,
                                            const float* __restrict__ wproj,
                                            const float* __restrict__ fcbin,
                                            const float* __restrict__ pose,
                                            __hip_bfloat16* __restrict__ fuse,
                                            __hip_bfloat16* __restrict__ wqkv16,
                                            __hip_bfloat16* __restrict__ wproj16,
                                            __hip_bfloat16* __restrict__ fcbinT16) {
    __shared__ __align__(16) char smem[47552];
    int b = blockIdx.x, tid = threadIdx.x;
    if (b < 3840) {
        float* lds  = (float*)smem;
        float* hbuf = (float*)(smem + 45056);
        int*   mi_s = (int*)(smem + 47104);
        if (tid < 112) mi_s[tid] = min_idx[tid];
        long long base = (long long)b * 11264;
        int w = tid >> 6, lane = tid & 63;
        const char* gsrc = (const char*)(sil + base) + lane * 16;
        #pragma unroll
        for (int i = 0; i < 11; i++) {
            int ci = w * 11 + i;
            gl_lds16(gsrc + ci * 1024, (char*)smem + ci * 1024);
        }
        __syncthreads();
        #pragma unroll
        for (int rr = 0; rr < 2; rr++) {
            int r = tid + rr * 256;
            const float* row = lds + r * 22;
            float s = 0.f, m = -INFINITY;
            #pragma unroll
            for (int k = 0; k < WW; k++) { float v = row[k]; s += v; m = fmaxf(m, v); }
            hbuf[r] = s * (1.0f / WW) + m;
        }
        __syncthreads();
        int q0 = b * 8;
        for (int idx = tid; idx < 8 * PP * MAXH; idx += 256) {
            int hh = idx % MAXH;
            int t2 = idx / MAXH;
            int j = t2 % PP, qi = t2 / PP;
            int q = q0 + qi;
            int s_i = q % SS, t3 = q / SS;
            int c = t3 & 63, n = t3 >> 6;
            int mi = mi_s[j * NN + n];
            fuse[((long long)(j * NS + n * SS + s_i)) * DD + c * MAXH + hh] =
                __float2bfloat16(hbuf[qi * 64 + mi + hh]);
        }
        return;
    }
    b -= 3840;
    if (b < 768)  { int g = b * 256 + tid; wqkv16[g] = __float2bfloat16(wqkv[g]); return; }
    if (b < 1024) { int g = (b - 768) * 256 + tid; wproj16[g] = __float2bfloat16(wproj[g]); return; }
    if (b < 1696) {
        float (*t)[65] = (float(*)[65])smem;
        int bb = b - 1024;
        int p = bb / 96, r2 = bb % 96, dt = r2 / 4, ot = r2 % 4;
        const float* s = fcbin + ((long long)p * DD + dt * 64) * OC + ot * 64;
        for (int i = tid; i < 64 * 64; i += 256) {
            int r = i >> 6, c = i & 63;
            t[r][c] = s[(long long)r * OC + c];
        }
        __syncthreads();
        __hip_bfloat16* d = fcbinT16 + ((long long)p * OC + ot * 64) * DD + dt * 64;
        for (int i = tid; i < 64 * 64; i += 256) {
            int r = i >> 6, c = i & 63;
            d[(long long)r * DD + c] = __float2bfloat16(t[c][r]);
        }
        return;
    }
    int g = (b - 1696) * 256 + tid;
    int dd = g & 127;
    int t2 = g >> 7;
    int nsi = t2 % NS;
    int j = t2 / NS;
    int n = nsi / SS, s_i = nsi % SS;
    int cpi = dd >> 1, par = dd & 1;
    const float* pr = pose + (((long long)n * CP + cpi) * SS + s_i) * VV;
    float v;
    if (j == 0) {
        v = (par == 0) ? (pr[0] + pr[1] + pr[2]) * (1.f / 3.f)
                       : (pr[2] + pr[3] + pr[4]) * (1.f / 3.f);
    } else {
        v = pr[5 + (j - 1) * 2 + par];
    }
    v = (v > 0.f) ? v : 0.01f * v;
    fuse[(long long)(j * NS + nsi) * DD + SILD + dd] = __float2bfloat16(v);
}

// ============ K2: fc MFMA GEMM, 64x64 tile, 8 waves K-split, XCD-swizzled grid, + BN partials ============
__global__ __launch_bounds__(512) void gemm_fc(
    const __hip_bfloat16* __restrict__ Ain, const __hip_bfloat16* __restrict__ Bt,
    float* __restrict__ Cf, float* __restrict__ partial)
{
    const int M = 480, K = 1536, lda = 1536, ldc = 1792;
    // XCD-aware bijective swizzle: 224 blocks = 28 per XCD (x fastest within chunk
    // -> 8 consecutive virtual blocks share one B-slab on the same XCD's L2)
    int bid = blockIdx.x;
    int v = (bid & 7) * 28 + (bid >> 3);
    int bz = v >> 5;             // part 0..6
    int rem = v & 31;
    int by = rem >> 3, bx = rem & 7;

    const __hip_bfloat16* Ab = Ain + (long long)bz * 480 * 1536;
    const __hip_bfloat16* Bq = Bt + (long long)bz * 256 * 1536;
    float* C = Cf + (long long)bz * 256;

    __shared__ short As[2][2][4096];      // [kgroup][buf]
    __shared__ short Bs[2][2][4096];
    __shared__ float red[4][2][16][2];

    int tid = threadIdx.x, lane = tid & 63, w = tid >> 6;   // w: 0..7
    int kg = w >> 2, wq = w & 3;
    int wm = wq >> 1, wn = wq & 1;
    int row0 = bx * 64, col0 = by * 64;
    int kbase = kg * 768;

    f32x4 acc[2][2] = {};

    auto stage = [&](int buf, int k0) {
        int cc = lane & 7;
        #pragma unroll
        for (int i = 0; i < 2; i++) {
            int r = wq * 16 + i * 8 + (lane >> 3);
            int grow = row0 + r; if (grow >= M) grow = M - 1;
            long long kk = kbase + k0;
            const char* ga = (const char*)Ab + (((long long)grow * lda + kk) << 1) + ((cc ^ (r & 7)) << 4);
            gl_lds16(ga, (char*)&As[kg][buf][0] + (wq * 16 + i * 8) * 128);
            const char* gb = (const char*)Bq + (((long long)(col0 + r) * K + kk) << 1) + ((cc ^ (r & 7)) << 4);
            gl_lds16(gb, (char*)&Bs[kg][buf][0] + (wq * 16 + i * 8) * 128);
        }
    };

    stage(0, 0);
    __syncthreads();
    for (int t = 0; t < 12; t++) {
        int cur = t & 1;
        if (t + 1 < 12) stage(cur ^ 1, (t + 1) << 6);
        #pragma unroll
        for (int ks = 0; ks < 2; ks++) {
            bf16x8 af[2], bfv[2];
            #pragma unroll
            for (int f = 0; f < 2; f++) {
                int r = wm * 32 + f * 16 + (lane & 15);
                int ca = (ks * 4 + (lane >> 4)) ^ (r & 7);
                af[f] = *(const bf16x8*)((const char*)&As[kg][cur][0] + r * 128 + (ca << 4));
                int rb = wn * 32 + f * 16 + (lane & 15);
                int cb = (ks * 4 + (lane >> 4)) ^ (rb & 7);
                bfv[f] = *(const bf16x8*)((const char*)&Bs[kg][cur][0] + rb * 128 + (cb << 4));
            }
            #pragma unroll
            for (int fm = 0; fm < 2; fm++)
                #pragma unroll
                for (int fn = 0; fn < 2; fn++)
                    acc[fm][fn] = __builtin_amdgcn_mfma_f32_16x16x32_bf16(
                        af[fm], bfv[fn], acc[fm][fn], 0, 0, 0);
        }
        __syncthreads();
    }

    float* redC = (float*)&As[0][0][0];
    if (kg == 1) {
        #pragma unroll
        for (int fm = 0; fm < 2; fm++)
            #pragma unroll
            for (int fn = 0; fn < 2; fn++)
                #pragma unroll
                for (int r4 = 0; r4 < 4; r4++) {
                    int rl = wm * 32 + fm * 16 + (lane >> 4) * 4 + r4;
                    int cl = wn * 32 + fn * 16 + (lane & 15);
                    redC[rl * 64 + cl] = acc[fm][fn][r4];
                }
    }
    __syncthreads();

    if (kg == 0) {
        float s[2] = {0.f, 0.f}, s2[2] = {0.f, 0.f};
        #pragma unroll
        for (int fm = 0; fm < 2; fm++) {
            #pragma unroll
            for (int fn = 0; fn < 2; fn++) {
                #pragma unroll
                for (int r4 = 0; r4 < 4; r4++) {
                    int rl = wm * 32 + fm * 16 + (lane >> 4) * 4 + r4;
                    int cl = wn * 32 + fn * 16 + (lane & 15);
                    int grow = row0 + rl;
                    if (grow < M) {
                        float vv = acc[fm][fn][r4] + redC[rl * 64 + cl];
                        C[(long long)grow * ldc + col0 + cl] = vv;
                        s[fn] += vv; s2[fn] += vv * vv;
                    }
                }
            }
        }
        #pragma unroll
        for (int off = 16; off < 64; off <<= 1) {
            s[0] += __shfl_xor(s[0], off);  s2[0] += __shfl_xor(s2[0], off);
            s[1] += __shfl_xor(s[1], off);  s2[1] += __shfl_xor(s2[1], off);
        }
        if (lane < 16) {
            red[wq][0][lane][0] = s[0]; red[wq][0][lane][1] = s2[0];
            red[wq][1][lane][0] = s[1]; red[wq][1][lane][1] = s2[1];
        }
    }
    __syncthreads();
    if (tid < 128) {
        int col = tid >> 1, which = tid & 1;
        int wn2 = (col >> 5) & 1, fn2 = (col >> 4) & 1, c16 = col & 15;
        float vv = red[wn2][fn2][c16][which] + red[2 + wn2][fn2][c16][which];
        partial[((long long)(bz * 8 + bx) * 2 + which) * 256 + by * 64 + col] = vv;
    }
}

// ============ K3: qkv GEMM [3360x256]*[768x256]^T -> bf16, BN-final recomputed inline ============
__global__ __launch_bounds__(256) void gemm_qkv(
    const float* __restrict__ xraw, const __hip_bfloat16* __restrict__ Bt,
    const float* __restrict__ partial, const float* __restrict__ gamma,
    const float* __restrict__ beta, float* __restrict__ ssbuf,
    __hip_bfloat16* __restrict__ qkv16)
{
    const int M = 3360, K = 256;
    __shared__ short As[2][4096];
    __shared__ short Bs[2][4096];
    __shared__ float ssl[512];
    int tid = threadIdx.x, lane = tid & 63, w = tid >> 6;
    int wm = w >> 1, wn = w & 1;
    int row0 = blockIdx.x * 64, col0 = blockIdx.y * 64;

    // inline BN-final (deterministic fixed-order sum; partial is L2-hot 114 KB)
    {
        float s = 0.f, s2 = 0.f;
        #pragma unroll 8
        for (int bb = 0; bb < 56; bb++) {
            s  += partial[bb * 512 + tid];
            s2 += partial[bb * 512 + 256 + tid];
        }
        float mu = s * (1.f / NTOK);
        float var = s2 * (1.f / NTOK) - mu * mu;
        float rsig = rsqrtf(var + 1e-5f);
        float sc = gamma[tid] * rsig;
        float sh = beta[tid] - mu * sc;
        ssl[tid] = sc;
        ssl[256 + tid] = sh;
        if (blockIdx.x == 0 && blockIdx.y == 0) {   // publish for attnproj
            ssbuf[tid] = sc;
            ssbuf[256 + tid] = sh;
        }
    }
    __syncthreads();

    f32x4 acc[2][2] = {};

    auto stageB = [&](int buf, int k0) {
        int cc = lane & 7;
        #pragma unroll
        for (int i = 0; i < 2; i++) {
            int r = w * 16 + i * 8 + (lane >> 3);
            const char* gb = (const char*)Bt + (((long long)(col0 + r) * K + k0) << 1) + ((cc ^ (r & 7)) << 4);
            gl_lds16(gb, (char*)&Bs[buf][0] + (w * 16 + i * 8) * 128);
        }
    };
    auto stageA = [&](int buf, int k0) {
        #pragma unroll
        for (int i = 0; i < 2; i++) {
            int id = tid + i * 256;
            int r = id >> 3, c8 = id & 7;
            int grow = row0 + r; if (grow >= M) grow = M - 1;
            const float* src = xraw + (long long)grow * 256 + k0 + c8 * 8;
            float4 v0 = *(const float4*)src;
            float4 v1 = *(const float4*)(src + 4);
            int kb = k0 + c8 * 8;
            float vv[8] = {v0.x, v0.y, v0.z, v0.w, v1.x, v1.y, v1.z, v1.w};
            short8 o;
            #pragma unroll
            for (int j = 0; j < 8; j++) {
                float tv = vv[j] * ssl[kb + j] + ssl[256 + kb + j];
                union { __hip_bfloat16 h; short s; } u; u.h = __float2bfloat16(tv);
                o[j] = u.s;
            }
            *(short8*)((char*)&As[buf][0] + r * 128 + ((c8 ^ (r & 7)) << 4)) = o;
        }
    };

    stageA(0, 0); stageB(0, 0);
    __syncthreads();
    for (int t = 0; t < 4; t++) {
        int cur = t & 1;
        if (t + 1 < 4) { stageA(cur ^ 1, (t + 1) << 6); stageB(cur ^ 1, (t + 1) << 6); }
        #pragma unroll
        for (int ks = 0; ks < 2; ks++) {
            bf16x8 af[2], bfv[2];
            #pragma unroll
            for (int f = 0; f < 2; f++) {
                int r = wm * 32 + f * 16 + (lane & 15);
                int ca = (ks * 4 + (lane >> 4)) ^ (r & 7);
                af[f] = *(const bf16x8*)((const char*)&As[cur][0] + r * 128 + (ca << 4));
                int rb = wn * 32 + f * 16 + (lane & 15);
                int cb = (ks * 4 + (lane >> 4)) ^ (rb & 7);
                bfv[f] = *(const bf16x8*)((const char*)&Bs[cur][0] + rb * 128 + (cb << 4));
            }
            #pragma unroll
            for (int fm = 0; fm < 2; fm++)
                #pragma unroll
                for (int fn = 0; fn < 2; fn++)
                    acc[fm][fn] = __builtin_amdgcn_mfma_f32_16x16x32_bf16(
                        af[fm], bfv[fn], acc[fm][fn], 0, 0, 0);
        }
        __syncthreads();
    }
    #pragma unroll
    for (int fm = 0; fm < 2; fm++)
        #pragma unroll
        for (int fn = 0; fn < 2; fn++)
            #pragma unroll
            for (int r4 = 0; r4 < 4; r4++) {
                int grow = row0 + wm * 32 + fm * 16 + (lane >> 4) * 4 + r4;
                int gcol = col0 + wn * 32 + fn * 16 + (lane & 15);
                if (grow < M)
                    qkv16[(long long)grow * 768 + gcol] = __float2bfloat16(acc[fm][fn][r4]);
            }
}

// ============ K4: attention + proj + residual + transposed out (480 blocks x 7 tokens) ============
__global__ __launch_bounds__(256) void attnproj(const __hip_bfloat16* __restrict__ qkv16,
                                                const __hip_bfloat16* __restrict__ wproj16,
                                                const float* __restrict__ xraw,
                                                const float* __restrict__ ssb,
                                                float* __restrict__ outp) {
    __shared__ __align__(16) char sm[33728];
    float* qkvs = (float*)sm;
    float* Ct   = (float*)sm;
    short* ao_s = (short*)(sm + 21728);
    float (*as_)[49] = (float(*)[49])(sm + 29920);
    float* ssl  = (float*)(sm + 31680);

    int tid = threadIdx.x, lane = tid & 63, w = tid >> 6;
    int token0 = blockIdx.x * 7;

    for (int i = tid; i < 512; i += 256) ssl[i] = ssb[i];

    const short* src = (const short*)qkv16 + (long long)token0 * 768;
    for (int c = tid; c < 672; c += 256) {
        int r = c / 96, c8 = (c % 96) * 8;
        short8 v = *(const short8*)(src + r * 768 + c8);
        float4 f0, f1;
        f0.x = bf2f(v[0]); f0.y = bf2f(v[1]); f0.z = bf2f(v[2]); f0.w = bf2f(v[3]);
        f1.x = bf2f(v[4]); f1.y = bf2f(v[5]); f1.z = bf2f(v[6]); f1.w = bf2f(v[7]);
        *(float4*)&qkvs[r * LDQ + c8] = f0;
        *(float4*)&qkvs[r * LDQ + c8 + 4] = f1;
    }
    __syncthreads();

    for (int t = tid; t < 392; t += 256) {
        int h = t / 49, ij = t % 49, i = ij / 7, j = ij % 7;
        const float* qp = qkvs + i * LDQ + h * 32;
        const float* kp = qkvs + j * LDQ + 256 + h * 32;
        float acc = 0.f;
        #pragma unroll
        for (int d = 0; d < 32; d++) acc += qp[d] * kp[d];
        as_[h][ij] = acc * 0.17677669529663689f;
    }
    __syncthreads();
    if (tid < 49) {
        float m = -INFINITY;
        #pragma unroll
        for (int h = 0; h < 8; h++) m = fmaxf(m, as_[h][tid]);
        float e[8], sum = 0.f;
        #pragma unroll
        for (int h = 0; h < 8; h++) { e[h] = __expf(as_[h][tid] - m); sum += e[h]; }
        float inv = 1.f / sum;
        #pragma unroll
        for (int h = 0; h < 8; h++) as_[h][tid] = e[h] * inv;
    }
    __syncthreads();
    #pragma unroll
    for (int tl = 0; tl < 16; tl++) {
        int col = tid;
        float acc = 0.f;
        if (tl < 7) {
            int h = col >> 5;
            const float* ap = &as_[h][tl * 7];
            const float* vp = qkvs + 512 + col;
            #pragma unroll
            for (int j = 0; j < 7; j++) acc += ap[j] * vp[j * LDQ];
        }
        int c16 = col >> 3;
        union { __hip_bfloat16 h2; short s2; } u; u.h2 = __float2bfloat16(acc);
        ao_s[tl * 256 + ((c16 ^ (tl & 7)) << 3) + (col & 7)] = u.s2;
    }
    __syncthreads();
    f32x4 pacc[4] = {};
    int n0 = w * 64;
    #pragma unroll
    for (int k0 = 0; k0 < 256; k0 += 32) {
        int rowa = lane & 15;
        int kk = k0 + (lane >> 4) * 8;
        int c16a = kk >> 3;
        bf16x8 af = *(const bf16x8*)(const void*)&ao_s[rowa * 256 + ((c16a ^ (rowa & 7)) << 3)];
        #pragma unroll
        for (int fn = 0; fn < 4; fn++) {
            int n = n0 + fn * 16 + (lane & 15);
            bf16x8 bfv = *(const bf16x8*)(const void*)((const short*)wproj16 + n * 256 + kk);
            pacc[fn] = __builtin_amdgcn_mfma_f32_16x16x32_bf16(af, bfv, pacc[fn], 0, 0, 0);
        }
    }
    __syncthreads();
    #pragma unroll
    for (int fn = 0; fn < 4; fn++)
        #pragma unroll
        for (int r4 = 0; r4 < 4; r4++) {
            int tk = (lane >> 4) * 4 + r4;
            if (tk < 7) {
                int o = n0 + fn * 16 + (lane & 15);
                Ct[o * 9 + tk] = pacc[fn][r4];
            }
        }
    __syncthreads();
    int o = tid;
    int n = token0 / 210, rem0 = token0 % 210;
    float* op = outp + ((long long)(n * 256 + o)) * 210 + rem0;
    float sc = ssl[o], sh = ssl[256 + o];
    #pragma unroll
    for (int tk = 0; tk < 7; tk++) {
        op[tk] = Ct[o * 9 + tk] + xraw[(long long)(token0 + tk) * 256 + o] * sc + sh;
    }
}

extern "C" void kernel_launch(void* const* d_in, const int* in_sizes, int n_in,
                              void* d_out, int out_size, void* d_ws, size_t ws_size,
                              hipStream_t stream) {
    const float* sil   = (const float*)d_in[0];
    const float* pose  = (const float*)d_in[1];
    const float* fcbin = (const float*)d_in[2];
    const float* gamma = (const float*)d_in[3];
    const float* beta  = (const float*)d_in[4];
    const float* wqkv  = (const float*)d_in[5];
    const float* wproj = (const float*)d_in[6];
    const int*   minidx= (const int*)d_in[7];
    float* out = (float*)d_out;

    float* ws = (float*)d_ws;
    __hip_bfloat16* fuse16   = (__hip_bfloat16*)ws;             // 5,160,960 bf16
    float* xraw    = ws + 2580480;                              // 860,160 f32 (ldc=1792 view)
    float* partial = ws + 3440640;                              // 28,672
    float* ssbuf   = ws + 3469312;                              // 512
    __hip_bfloat16* wqkv16   = (__hip_bfloat16*)(ws + 3469824); // 196,608 bf16
    __hip_bfloat16* wproj16  = (__hip_bfloat16*)(ws + 3568128); // 65,536 bf16
    __hip_bfloat16* fcbinT16 = (__hip_bfloat16*)(ws + 3600896); // 2,752,512 bf16
    __hip_bfloat16* qkv16    = (__hip_bfloat16*)(ws + 4977152); // 2,580,480 bf16

    prep<<<7216, 256, 0, stream>>>(sil, minidx, wqkv, wproj, fcbin, pose,
                                   fuse16, wqkv16, wproj16, fcbinT16);
    gemm_fc<<<224, 512, 0, stream>>>(fuse16, fcbinT16, xraw, partial);
    gemm_qkv<<<dim3(53, 12), 256, 0, stream>>>(xraw, wqkv16, partial, gamma, beta, ssbuf, qkv16);
    attnproj<<<480, 256, 0, stream>>>(qkv16, wproj16, xraw, ssbuf, out);
}

// Round 16
// 77.685 us; speedup vs baseline: 11.5858x; 1.0132x over previous
//
#include <hip/hip_runtime.h>
#include <hip/hip_bf16.h>
#include <math.h>

#define NS 480   // n*s
#define NN 16
#define SS 30
#define CC 64
#define HHH 64
#define WW 22
#define PP 7
#define MAXH 22
#define CP 64
#define VV 17
#define DD 1536
#define OC 256
#define SILD 1408   // c*MAXH
#define NTOK 3360   // NS*PP
#define LDQ 776

typedef __bf16 bf16x8 __attribute__((ext_vector_type(8)));
typedef float f32x4 __attribute__((ext_vector_type(4)));
typedef short short8 __attribute__((ext_vector_type(8)));

__device__ __forceinline__ void gl_lds16(const void* g, void* l) {
    __builtin_amdgcn_global_load_lds(
        (const __attribute__((address_space(1))) void*)g,
        (__attribute__((address_space(3))) void*)l, 16, 0, 0);
}

__device__ __forceinline__ float bf2f(short s) {
    union { float f; unsigned u; } uu; uu.u = ((unsigned)(unsigned short)s) << 16; return uu.f;
}

// ============ K1: pool+gather (8 triples/block, gl_lds streaming) + weight/pose prep ============
__global__ __launch_bounds__(256) void prep(const float* __restrict__ sil,
                                            const int* __restrict__ min_idx,
                                            const float* __restrict__ wqkv,
                                            const float* __restrict__ wproj,
                                            const float* __restrict__ fcbin,
                                            const float* __restrict__ pose,
                                            __hip_bfloat16* __restrict__ fuse,
                                            __hip_bfloat16* __restrict__ wqkv16,
                                            __hip_bfloat16* __restrict__ wproj16,
                                            __hip_bfloat16* __restrict__ fcbinT16) {
    __shared__ __align__(16) char smem[47552];
    int b = blockIdx.x, tid = threadIdx.x;
    if (b < 3840) {
        float* lds  = (float*)smem;
        float* hbuf = (float*)(smem + 45056);
        int*   mi_s = (int*)(smem + 47104);
        if (tid < 112) mi_s[tid] = min_idx[tid];
        long long base = (long long)b * 11264;
        int w = tid >> 6, lane = tid & 63;
        const char* gsrc = (const char*)(sil + base) + lane * 16;
        #pragma unroll
        for (int i = 0; i < 11; i++) {
            int ci = w * 11 + i;
            gl_lds16(gsrc + ci * 1024, (char*)smem + ci * 1024);
        }
        __syncthreads();
        #pragma unroll
        for (int rr = 0; rr < 2; rr++) {
            int r = tid + rr * 256;
            const float* row = lds + r * 22;
            float s = 0.f, m = -INFINITY;
            #pragma unroll
            for (int k = 0; k < WW; k++) { float v = row[k]; s += v; m = fmaxf(m, v); }
            hbuf[r] = s * (1.0f / WW) + m;
        }
        __syncthreads();
        int q0 = b * 8;
        for (int idx = tid; idx < 8 * PP * MAXH; idx += 256) {
            int hh = idx % MAXH;
            int t2 = idx / MAXH;
            int j = t2 % PP, qi = t2 / PP;
            int q = q0 + qi;
            int s_i = q % SS, t3 = q / SS;
            int c = t3 & 63, n = t3 >> 6;
            int mi = mi_s[j * NN + n];
            fuse[((long long)(j * NS + n * SS + s_i)) * DD + c * MAXH + hh] =
                __float2bfloat16(hbuf[qi * 64 + mi + hh]);
        }
        return;
    }
    b -= 3840;
    if (b < 768)  { int g = b * 256 + tid; wqkv16[g] = __float2bfloat16(wqkv[g]); return; }
    if (b < 1024) { int g = (b - 768) * 256 + tid; wproj16[g] = __float2bfloat16(wproj[g]); return; }
    if (b < 1696) {
        float (*t)[65] = (float(*)[65])smem;
        int bb = b - 1024;
        int p = bb / 96, r2 = bb % 96, dt = r2 / 4, ot = r2 % 4;
        const float* s = fcbin + ((long long)p * DD + dt * 64) * OC + ot * 64;
        for (int i = tid; i < 64 * 64; i += 256) {
            int r = i >> 6, c = i & 63;
            t[r][c] = s[(long long)r * OC + c];
        }
        __syncthreads();
        __hip_bfloat16* d = fcbinT16 + ((long long)p * OC + ot * 64) * DD + dt * 64;
        for (int i = tid; i < 64 * 64; i += 256) {
            int r = i >> 6, c = i & 63;
            d[(long long)r * DD + c] = __float2bfloat16(t[c][r]);
        }
        return;
    }
    int g = (b - 1696) * 256 + tid;
    int dd = g & 127;
    int t2 = g >> 7;
    int nsi = t2 % NS;
    int j = t2 / NS;
    int n = nsi / SS, s_i = nsi % SS;
    int cpi = dd >> 1, par = dd & 1;
    const float* pr = pose + (((long long)n * CP + cpi) * SS + s_i) * VV;
    float v;
    if (j == 0) {
        v = (par == 0) ? (pr[0] + pr[1] + pr[2]) * (1.f / 3.f)
                       : (pr[2] + pr[3] + pr[4]) * (1.f / 3.f);
    } else {
        v = pr[5 + (j - 1) * 2 + par];
    }
    v = (v > 0.f) ? v : 0.01f * v;
    fuse[(long long)(j * NS + nsi) * DD + SILD + dd] = __float2bfloat16(v);
}

// ============ K2: fc MFMA GEMM, 64x64 tile, 8 waves K-split, XCD-swizzled grid, + BN partials ============
__global__ __launch_bounds__(512) void gemm_fc(
    const __hip_bfloat16* __restrict__ Ain, const __hip_bfloat16* __restrict__ Bt,
    float* __restrict__ Cf, float* __restrict__ partial)
{
    const int M = 480, K = 1536, lda = 1536, ldc = 1792;
    int bid = blockIdx.x;
    int v = (bid & 7) * 28 + (bid >> 3);
    int bz = v >> 5;             // part 0..6
    int rem = v & 31;
    int by = rem >> 3, bx = rem & 7;

    const __hip_bfloat16* Ab = Ain + (long long)bz * 480 * 1536;
    const __hip_bfloat16* Bq = Bt + (long long)bz * 256 * 1536;
    float* C = Cf + (long long)bz * 256;

    __shared__ short As[2][2][4096];      // [kgroup][buf]
    __shared__ short Bs[2][2][4096];
    __shared__ float red[4][2][16][2];

    int tid = threadIdx.x, lane = tid & 63, w = tid >> 6;   // w: 0..7
    int kg = w >> 2, wq = w & 3;
    int wm = wq >> 1, wn = wq & 1;
    int row0 = bx * 64, col0 = by * 64;
    int kbase = kg * 768;

    f32x4 acc[2][2] = {};

    auto stage = [&](int buf, int k0) {
        int cc = lane & 7;
        #pragma unroll
        for (int i = 0; i < 2; i++) {
            int r = wq * 16 + i * 8 + (lane >> 3);
            int grow = row0 + r; if (grow >= M) grow = M - 1;
            long long kk = kbase + k0;
            const char* ga = (const char*)Ab + (((long long)grow * lda + kk) << 1) + ((cc ^ (r & 7)) << 4);
            gl_lds16(ga, (char*)&As[kg][buf][0] + (wq * 16 + i * 8) * 128);
            const char* gb = (const char*)Bq + (((long long)(col0 + r) * K + kk) << 1) + ((cc ^ (r & 7)) << 4);
            gl_lds16(gb, (char*)&Bs[kg][buf][0] + (wq * 16 + i * 8) * 128);
        }
    };

    stage(0, 0);
    __syncthreads();
    for (int t = 0; t < 12; t++) {
        int cur = t & 1;
        if (t + 1 < 12) stage(cur ^ 1, (t + 1) << 6);
        #pragma unroll
        for (int ks = 0; ks < 2; ks++) {
            bf16x8 af[2], bfv[2];
            #pragma unroll
            for (int f = 0; f < 2; f++) {
                int r = wm * 32 + f * 16 + (lane & 15);
                int ca = (ks * 4 + (lane >> 4)) ^ (r & 7);
                af[f] = *(const bf16x8*)((const char*)&As[kg][cur][0] + r * 128 + (ca << 4));
                int rb = wn * 32 + f * 16 + (lane & 15);
                int cb = (ks * 4 + (lane >> 4)) ^ (rb & 7);
                bfv[f] = *(const bf16x8*)((const char*)&Bs[kg][cur][0] + rb * 128 + (cb << 4));
            }
            #pragma unroll
            for (int fm = 0; fm < 2; fm++)
                #pragma unroll
                for (int fn = 0; fn < 2; fn++)
                    acc[fm][fn] = __builtin_amdgcn_mfma_f32_16x16x32_bf16(
                        af[fm], bfv[fn], acc[fm][fn], 0, 0, 0);
        }
        __syncthreads();
    }

    float* redC = (float*)&As[0][0][0];
    if (kg == 1) {
        #pragma unroll
        for (int fm = 0; fm < 2; fm++)
            #pragma unroll
            for (int fn = 0; fn < 2; fn++)
                #pragma unroll
                for (int r4 = 0; r4 < 4; r4++) {
                    int rl = wm * 32 + fm * 16 + (lane >> 4) * 4 + r4;
                    int cl = wn * 32 + fn * 16 + (lane & 15);
                    redC[rl * 64 + cl] = acc[fm][fn][r4];
                }
    }
    __syncthreads();

    if (kg == 0) {
        float s[2] = {0.f, 0.f}, s2[2] = {0.f, 0.f};
        #pragma unroll
        for (int fm = 0; fm < 2; fm++) {
            #pragma unroll
            for (int fn = 0; fn < 2; fn++) {
                #pragma unroll
                for (int r4 = 0; r4 < 4; r4++) {
                    int rl = wm * 32 + fm * 16 + (lane >> 4) * 4 + r4;
                    int cl = wn * 32 + fn * 16 + (lane & 15);
                    int grow = row0 + rl;
                    if (grow < M) {
                        float vv = acc[fm][fn][r4] + redC[rl * 64 + cl];
                        C[(long long)grow * ldc + col0 + cl] = vv;
                        s[fn] += vv; s2[fn] += vv * vv;
                    }
                }
            }
        }
        #pragma unroll
        for (int off = 16; off < 64; off <<= 1) {
            s[0] += __shfl_xor(s[0], off);  s2[0] += __shfl_xor(s2[0], off);
            s[1] += __shfl_xor(s[1], off);  s2[1] += __shfl_xor(s2[1], off);
        }
        if (lane < 16) {
            red[wq][0][lane][0] = s[0]; red[wq][0][lane][1] = s2[0];
            red[wq][1][lane][0] = s[1]; red[wq][1][lane][1] = s2[1];
        }
    }
    __syncthreads();
    if (tid < 128) {
        int col = tid >> 1, which = tid & 1;
        int wn2 = (col >> 5) & 1, fn2 = (col >> 4) & 1, c16 = col & 15;
        float vv = red[wn2][fn2][c16][which] + red[2 + wn2][fn2][c16][which];
        partial[((long long)(bz * 8 + bx) * 2 + which) * 256 + by * 64 + col] = vv;
    }
}

// ============ K3: qkv GEMM [3360x256]*[768x256]^T -> bf16, BN-final recomputed inline ============
__global__ __launch_bounds__(256) void gemm_qkv(
    const float* __restrict__ xraw, const __hip_bfloat16* __restrict__ Bt,
    const float* __restrict__ partial, const float* __restrict__ gamma,
    const float* __restrict__ beta, float* __restrict__ ssbuf,
    __hip_bfloat16* __restrict__ qkv16)
{
    const int M = 3360, K = 256;
    __shared__ short As[2][4096];
    __shared__ short Bs[2][4096];
    __shared__ float ssl[512];
    int tid = threadIdx.x, lane = tid & 63, w = tid >> 6;
    int wm = w >> 1, wn = w & 1;
    int row0 = blockIdx.x * 64, col0 = blockIdx.y * 64;

    {
        float s = 0.f, s2 = 0.f;
        #pragma unroll 8
        for (int bb = 0; bb < 56; bb++) {
            s  += partial[bb * 512 + tid];
            s2 += partial[bb * 512 + 256 + tid];
        }
        float mu = s * (1.f / NTOK);
        float var = s2 * (1.f / NTOK) - mu * mu;
        float rsig = rsqrtf(var + 1e-5f);
        float sc = gamma[tid] * rsig;
        float sh = beta[tid] - mu * sc;
        ssl[tid] = sc;
        ssl[256 + tid] = sh;
        if (blockIdx.x == 0 && blockIdx.y == 0) {
            ssbuf[tid] = sc;
            ssbuf[256 + tid] = sh;
        }
    }
    __syncthreads();

    f32x4 acc[2][2] = {};

    auto stageB = [&](int buf, int k0) {
        int cc = lane & 7;
        #pragma unroll
        for (int i = 0; i < 2; i++) {
            int r = w * 16 + i * 8 + (lane >> 3);
            const char* gb = (const char*)Bt + (((long long)(col0 + r) * K + k0) << 1) + ((cc ^ (r & 7)) << 4);
            gl_lds16(gb, (char*)&Bs[buf][0] + (w * 16 + i * 8) * 128);
        }
    };
    auto stageA = [&](int buf, int k0) {
        #pragma unroll
        for (int i = 0; i < 2; i++) {
            int id = tid + i * 256;
            int r = id >> 3, c8 = id & 7;
            int grow = row0 + r; if (grow >= M) grow = M - 1;
            const float* src = xraw + (long long)grow * 256 + k0 + c8 * 8;
            float4 v0 = *(const float4*)src;
            float4 v1 = *(const float4*)(src + 4);
            int kb = k0 + c8 * 8;
            float vv[8] = {v0.x, v0.y, v0.z, v0.w, v1.x, v1.y, v1.z, v1.w};
            short8 o;
            #pragma unroll
            for (int j = 0; j < 8; j++) {
                float tv = vv[j] * ssl[kb + j] + ssl[256 + kb + j];
                union { __hip_bfloat16 h; short s; } u; u.h = __float2bfloat16(tv);
                o[j] = u.s;
            }
            *(short8*)((char*)&As[buf][0] + r * 128 + ((c8 ^ (r & 7)) << 4)) = o;
        }
    };

    stageA(0, 0); stageB(0, 0);
    __syncthreads();
    for (int t = 0; t < 4; t++) {
        int cur = t & 1;
        if (t + 1 < 4) { stageA(cur ^ 1, (t + 1) << 6); stageB(cur ^ 1, (t + 1) << 6); }
        #pragma unroll
        for (int ks = 0; ks < 2; ks++) {
            bf16x8 af[2], bfv[2];
            #pragma unroll
            for (int f = 0; f < 2; f++) {
                int r = wm * 32 + f * 16 + (lane & 15);
                int ca = (ks * 4 + (lane >> 4)) ^ (r & 7);
                af[f] = *(const bf16x8*)((const char*)&As[cur][0] + r * 128 + (ca << 4));
                int rb = wn * 32 + f * 16 + (lane & 15);
                int cb = (ks * 4 + (lane >> 4)) ^ (rb & 7);
                bfv[f] = *(const bf16x8*)((const char*)&Bs[cur][0] + rb * 128 + (cb << 4));
            }
            #pragma unroll
            for (int fm = 0; fm < 2; fm++)
                #pragma unroll
                for (int fn = 0; fn < 2; fn++)
                    acc[fm][fn] = __builtin_amdgcn_mfma_f32_16x16x32_bf16(
                        af[fm], bfv[fn], acc[fm][fn], 0, 0, 0);
        }
        __syncthreads();
    }
    #pragma unroll
    for (int fm = 0; fm < 2; fm++)
        #pragma unroll
        for (int fn = 0; fn < 2; fn++)
            #pragma unroll
            for (int r4 = 0; r4 < 4; r4++) {
                int grow = row0 + wm * 32 + fm * 16 + (lane >> 4) * 4 + r4;
                int gcol = col0 + wn * 32 + fn * 16 + (lane & 15);
                if (grow < M)
                    qkv16[(long long)grow * 768 + gcol] = __float2bfloat16(acc[fm][fn][r4]);
            }
}

// ============ K4: attention + proj(swapped operands) + residual + DIRECT transposed out ============
// 480 blocks x 7 tokens; 4 barriers (was 6); no Ct round-trip.
__global__ __launch_bounds__(256) void attnproj(const __hip_bfloat16* __restrict__ qkv16,
                                                const __hip_bfloat16* __restrict__ wproj16,
                                                const float* __restrict__ xraw,
                                                const float* __restrict__ ssb,
                                                float* __restrict__ outp) {
    __shared__ __align__(16) char sm[40736];
    float* qkvs  = (float*)sm;                        // [7*LDQ] f32 = 21728 B
    short* ao_s  = (short*)(sm + 21728);              // [16*256] bf16 = 8192 B
    float* res_s = (float*)(sm + 29920);              // [7*257] f32 = 7196 B (BN applied)
    float (*as_)[49] = (float(*)[49])(sm + 37120);    // 1568 B

    int tid = threadIdx.x, lane = tid & 63, w = tid >> 6;
    int token0 = blockIdx.x * 7;

    // phase 1: qkv rows -> padded f32 LDS; BN(residual) rows -> res_s (coalesced)
    const short* src = (const short*)qkv16 + (long long)token0 * 768;
    for (int c = tid; c < 672; c += 256) {
        int r = c / 96, c8 = (c % 96) * 8;
        short8 v = *(const short8*)(src + r * 768 + c8);
        float4 f0, f1;
        f0.x = bf2f(v[0]); f0.y = bf2f(v[1]); f0.z = bf2f(v[2]); f0.w = bf2f(v[3]);
        f1.x = bf2f(v[4]); f1.y = bf2f(v[5]); f1.z = bf2f(v[6]); f1.w = bf2f(v[7]);
        *(float4*)&qkvs[r * LDQ + c8] = f0;
        *(float4*)&qkvs[r * LDQ + c8 + 4] = f1;
    }
    {
        float sc = ssb[tid], sh = ssb[256 + tid];
        #pragma unroll
        for (int r = 0; r < 7; r++)
            res_s[r * 257 + tid] = xraw[(long long)(token0 + r) * 256 + tid] * sc + sh;
    }
    __syncthreads();

    // phase 2: attention scores (softmax over HEADS)
    for (int t = tid; t < 392; t += 256) {
        int h = t / 49, ij = t % 49, i = ij / 7, j = ij % 7;
        const float* qp = qkvs + i * LDQ + h * 32;
        const float* kp = qkvs + j * LDQ + 256 + h * 32;
        float acc = 0.f;
        #pragma unroll
        for (int d = 0; d < 32; d++) acc += qp[d] * kp[d];
        as_[h][ij] = acc * 0.17677669529663689f;
    }
    __syncthreads();
    // phase 3: softmax over heads
    if (tid < 49) {
        float m = -INFINITY;
        #pragma unroll
        for (int h = 0; h < 8; h++) m = fmaxf(m, as_[h][tid]);
        float e[8], sum = 0.f;
        #pragma unroll
        for (int h = 0; h < 8; h++) { e[h] = __expf(as_[h][tid] - m); sum += e[h]; }
        float inv = 1.f / sum;
        #pragma unroll
        for (int h = 0; h < 8; h++) as_[h][tid] = e[h] * inv;
    }
    __syncthreads();
    // phase 4: ao rows (pads zero), XOR-swizzled bf16 store
    #pragma unroll
    for (int tl = 0; tl < 16; tl++) {
        int col = tid;
        float acc = 0.f;
        if (tl < 7) {
            int h = col >> 5;
            const float* ap = &as_[h][tl * 7];
            const float* vp = qkvs + 512 + col;
            #pragma unroll
            for (int j = 0; j < 7; j++) acc += ap[j] * vp[j * LDQ];
        }
        int c16 = col >> 3;
        union { __hip_bfloat16 h2; short s2; } u; u.h2 = __float2bfloat16(acc);
        ao_s[tl * 256 + ((c16 ^ (tl & 7)) << 3) + (col & 7)] = u.s2;
    }
    __syncthreads();
    // phase 5: proj MFMA, SWAPPED operands: A = wproj rows (output row = o),
    // B = ao rows (output col = token). C[o][token] -> direct transposed write.
    f32x4 pacc[4] = {};
    int n0 = w * 64;
    #pragma unroll
    for (int k0 = 0; k0 < 256; k0 += 32) {
        int kk = k0 + (lane >> 4) * 8;
        int rowb = lane & 15;
        int c16b = kk >> 3;
        bf16x8 bfr = *(const bf16x8*)(const void*)&ao_s[rowb * 256 + ((c16b ^ (rowb & 7)) << 3)];
        #pragma unroll
        for (int fo = 0; fo < 4; fo++) {
            int o = n0 + fo * 16 + (lane & 15);
            bf16x8 afr = *(const bf16x8*)(const void*)((const short*)wproj16 + o * 256 + kk);
            pacc[fo] = __builtin_amdgcn_mfma_f32_16x16x32_bf16(afr, bfr, pacc[fo], 0, 0, 0);
        }
    }
    // direct write: o = n0 + fo*16 + (lane>>4)*4 + r4, token = lane&15 (valid < 7)
    int tk = lane & 15;
    if (tk < 7) {
        int n = token0 / 210, rem0 = token0 % 210;   // 210 = 30*7: never straddles n
        #pragma unroll
        for (int fo = 0; fo < 4; fo++)
            #pragma unroll
            for (int r4 = 0; r4 < 4; r4++) {
                int o = n0 + fo * 16 + (lane >> 4) * 4 + r4;
                outp[((long long)(n * 256 + o)) * 210 + rem0 + tk] =
                    pacc[fo][r4] + res_s[tk * 257 + o];
            }
    }
}

extern "C" void kernel_launch(void* const* d_in, const int* in_sizes, int n_in,
                              void* d_out, int out_size, void* d_ws, size_t ws_size,
                              hipStream_t stream) {
    const float* sil   = (const float*)d_in[0];
    const float* pose  = (const float*)d_in[1];
    const float* fcbin = (const float*)d_in[2];
    const float* gamma = (const float*)d_in[3];
    const float* beta  = (const float*)d_in[4];
    const float* wqkv  = (const float*)d_in[5];
    const float* wproj = (const float*)d_in[6];
    const int*   minidx= (const int*)d_in[7];
    float* out = (float*)d_out;

    float* ws = (float*)d_ws;
    __hip_bfloat16* fuse16   = (__hip_bfloat16*)ws;             // 5,160,960 bf16
    float* xraw    = ws + 2580480;                              // 860,160 f32 (ldc=1792 view)
    float* partial = ws + 3440640;                              // 28,672
    float* ssbuf   = ws + 3469312;                              // 512
    __hip_bfloat16* wqkv16   = (__hip_bfloat16*)(ws + 3469824); // 196,608 bf16
    __hip_bfloat16* wproj16  = (__hip_bfloat16*)(ws + 3568128); // 65,536 bf16
    __hip_bfloat16* fcbinT16 = (__hip_bfloat16*)(ws + 3600896); // 2,752,512 bf16
    __hip_bfloat16* qkv16    = (__hip_bfloat16*)(ws + 4977152); // 2,580,480 bf16

    prep<<<7216, 256, 0, stream>>>(sil, minidx, wqkv, wproj, fcbin, pose,
                                   fuse16, wqkv16, wproj16, fcbinT16);
    gemm_fc<<<224, 512, 0, stream>>>(fuse16, fcbinT16, xraw, partial);
    gemm_qkv<<<dim3(53, 12), 256, 0, stream>>>(xraw, wqkv16, partial, gamma, beta, ssbuf, qkv16);
    attnproj<<<480, 256, 0, stream>>>(qkv16, wproj16, xraw, ssbuf, out);
}

// Round 17
// 74.983 us; speedup vs baseline: 12.0033x; 1.0360x over previous
//
#include <hip/hip_runtime.h>
#include <hip/hip_bf16.h>
#include <math.h>

#define NS 480   // n*s
#define NN 16
#define SS 30
#define CC 64
#define HHH 64
#define WW 22
#define PP 7
#define MAXH 22
#define CP 64
#define VV 17
#define DD 1536
#define OC 256
#define SILD 1408   // c*MAXH
#define NTOK 3360   // NS*PP
#define LDQ 776

typedef __bf16 bf16x8 __attribute__((ext_vector_type(8)));
typedef float f32x4 __attribute__((ext_vector_type(4)));
typedef short short8 __attribute__((ext_vector_type(8)));

__device__ __forceinline__ void gl_lds16(const void* g, void* l) {
    __builtin_amdgcn_global_load_lds(
        (const __attribute__((address_space(1))) void*)g,
        (__attribute__((address_space(3))) void*)l, 16, 0, 0);
}

__device__ __forceinline__ float bf2f(short s) {
    union { float f; unsigned u; } uu; uu.u = ((unsigned)(unsigned short)s) << 16; return uu.f;
}

// ============ K1: pool+gather (c-major blocking: coalesced fuse writes) + weight/pose prep ============
__global__ __launch_bounds__(256) void prep(const float* __restrict__ sil,
                                            const int* __restrict__ min_idx,
                                            const float* __restrict__ wqkv,
                                            const float* __restrict__ wproj,
                                            const float* __restrict__ fcbin,
                                            const float* __restrict__ pose,
                                            __hip_bfloat16* __restrict__ fuse,
                                            __hip_bfloat16* __restrict__ wqkv16,
                                            __hip_bfloat16* __restrict__ wproj16,
                                            __hip_bfloat16* __restrict__ fcbinT16) {
    __shared__ __align__(16) char smem[47552];
    int b = blockIdx.x, tid = threadIdx.x;
    if (b < 3840) {
        // block = (n, s_i, c-octet): 8 consecutive-c triples; fuse writes coalesce (352B runs)
        float* lds  = (float*)smem;             // 11264 floats (8 triples x 1408)
        float* hbuf = (float*)(smem + 45056);   // 512 floats [t*64+h]
        int*   mi_s = (int*)(smem + 47104);     // 7 ints
        int n = b / 240, rem = b % 240, s_i = rem >> 3, oct = rem & 7;
        int c0 = oct << 3;
        if (tid < 7) mi_s[tid] = min_idx[tid * NN + n];
        int w = tid >> 6, lane = tid & 63;
        // wave w stages triples {2w, 2w+1}; triple t at q = (n*64 + c0 + t)*30 + s_i
        const char* baseA = (const char*)sil +
            (((long long)(n * 64 + c0 + 2 * w) * 30 + s_i) * 1408) * 4;
        const char* baseB = baseA + (long long)30 * 5632;   // next c (q + 30)
        #pragma unroll
        for (int i = 0; i < 11; i++) {
            int off = i * 1024 + lane * 16;      // byte offset within the 11264B pair
            const char* src = (off < 5632) ? (baseA + off) : (baseB + (off - 5632));
            gl_lds16(src, (char*)smem + w * 11264 + i * 1024);
        }
        __syncthreads();
        #pragma unroll
        for (int rr = 0; rr < 2; rr++) {
            int r = tid + rr * 256;              // 0..511 = t*64 + h
            int t = r >> 6, h = r & 63;
            const float* row = lds + (t >> 1) * 2816 + (t & 1) * 1408 + h * 22;
            float s = 0.f, m = -INFINITY;
            #pragma unroll
            for (int k = 0; k < WW; k++) { float v = row[k]; s += v; m = fmaxf(m, v); }
            hbuf[t * 64 + h] = s * (1.0f / WW) + m;
        }
        __syncthreads();
        // gather: 7 parts x 8 c x 22 hh = 1232 items; contiguous per part
        int nsi = n * SS + s_i;
        for (int idx = tid; idx < PP * 8 * MAXH; idx += 256) {
            int j = idx / 176, r2 = idx % 176;
            int cl = r2 / 22, hh = r2 % 22;
            int mi = mi_s[j];
            fuse[((long long)(j * NS + nsi)) * DD + (c0 + cl) * 22 + hh] =
                __float2bfloat16(hbuf[cl * 64 + mi + hh]);
        }
        return;
    }
    b -= 3840;
    if (b < 768)  { int g = b * 256 + tid; wqkv16[g] = __float2bfloat16(wqkv[g]); return; }
    if (b < 1024) { int g = (b - 768) * 256 + tid; wproj16[g] = __float2bfloat16(wproj[g]); return; }
    if (b < 1696) {
        float (*t)[65] = (float(*)[65])smem;
        int bb = b - 1024;
        int p = bb / 96, r2 = bb % 96, dt = r2 / 4, ot = r2 % 4;
        const float* s = fcbin + ((long long)p * DD + dt * 64) * OC + ot * 64;
        for (int i = tid; i < 64 * 64; i += 256) {
            int r = i >> 6, c = i & 63;
            t[r][c] = s[(long long)r * OC + c];
        }
        __syncthreads();
        __hip_bfloat16* d = fcbinT16 + ((long long)p * OC + ot * 64) * DD + dt * 64;
        for (int i = tid; i < 64 * 64; i += 256) {
            int r = i >> 6, c = i & 63;
            d[(long long)r * DD + c] = __float2bfloat16(t[c][r]);
        }
        return;
    }
    int g = (b - 1696) * 256 + tid;
    int dd = g & 127;
    int t2 = g >> 7;
    int nsi = t2 % NS;
    int j = t2 / NS;
    int n = nsi / SS, s_i = nsi % SS;
    int cpi = dd >> 1, par = dd & 1;
    const float* pr = pose + (((long long)n * CP + cpi) * SS + s_i) * VV;
    float v;
    if (j == 0) {
        v = (par == 0) ? (pr[0] + pr[1] + pr[2]) * (1.f / 3.f)
                       : (pr[2] + pr[3] + pr[4]) * (1.f / 3.f);
    } else {
        v = pr[5 + (j - 1) * 2 + par];
    }
    v = (v > 0.f) ? v : 0.01f * v;
    fuse[(long long)(j * NS + nsi) * DD + SILD + dd] = __float2bfloat16(v);
}

// ============ K2: fc MFMA GEMM, 64x64 tile, 8 waves K-split, XCD-swizzled grid, + BN partials ============
__global__ __launch_bounds__(512) void gemm_fc(
    const __hip_bfloat16* __restrict__ Ain, const __hip_bfloat16* __restrict__ Bt,
    float* __restrict__ Cf, float* __restrict__ partial)
{
    const int M = 480, K = 1536, lda = 1536, ldc = 1792;
    int bid = blockIdx.x;
    int v = (bid & 7) * 28 + (bid >> 3);
    int bz = v >> 5;             // part 0..6
    int rem = v & 31;
    int by = rem >> 3, bx = rem & 7;

    const __hip_bfloat16* Ab = Ain + (long long)bz * 480 * 1536;
    const __hip_bfloat16* Bq = Bt + (long long)bz * 256 * 1536;
    float* C = Cf + (long long)bz * 256;

    __shared__ short As[2][2][4096];      // [kgroup][buf]
    __shared__ short Bs[2][2][4096];
    __shared__ float red[4][2][16][2];

    int tid = threadIdx.x, lane = tid & 63, w = tid >> 6;   // w: 0..7
    int kg = w >> 2, wq = w & 3;
    int wm = wq >> 1, wn = wq & 1;
    int row0 = bx * 64, col0 = by * 64;
    int kbase = kg * 768;

    f32x4 acc[2][2] = {};

    auto stage = [&](int buf, int k0) {
        int cc = lane & 7;
        #pragma unroll
        for (int i = 0; i < 2; i++) {
            int r = wq * 16 + i * 8 + (lane >> 3);
            int grow = row0 + r; if (grow >= M) grow = M - 1;
            long long kk = kbase + k0;
            const char* ga = (const char*)Ab + (((long long)grow * lda + kk) << 1) + ((cc ^ (r & 7)) << 4);
            gl_lds16(ga, (char*)&As[kg][buf][0] + (wq * 16 + i * 8) * 128);
            const char* gb = (const char*)Bq + (((long long)(col0 + r) * K + kk) << 1) + ((cc ^ (r & 7)) << 4);
            gl_lds16(gb, (char*)&Bs[kg][buf][0] + (wq * 16 + i * 8) * 128);
        }
    };

    stage(0, 0);
    __syncthreads();
    for (int t = 0; t < 12; t++) {
        int cur = t & 1;
        if (t + 1 < 12) stage(cur ^ 1, (t + 1) << 6);
        #pragma unroll
        for (int ks = 0; ks < 2; ks++) {
            bf16x8 af[2], bfv[2];
            #pragma unroll
            for (int f = 0; f < 2; f++) {
                int r = wm * 32 + f * 16 + (lane & 15);
                int ca = (ks * 4 + (lane >> 4)) ^ (r & 7);
                af[f] = *(const bf16x8*)((const char*)&As[kg][cur][0] + r * 128 + (ca << 4));
                int rb = wn * 32 + f * 16 + (lane & 15);
                int cb = (ks * 4 + (lane >> 4)) ^ (rb & 7);
                bfv[f] = *(const bf16x8*)((const char*)&Bs[kg][cur][0] + rb * 128 + (cb << 4));
            }
            #pragma unroll
            for (int fm = 0; fm < 2; fm++)
                #pragma unroll
                for (int fn = 0; fn < 2; fn++)
                    acc[fm][fn] = __builtin_amdgcn_mfma_f32_16x16x32_bf16(
                        af[fm], bfv[fn], acc[fm][fn], 0, 0, 0);
        }
        __syncthreads();
    }

    float* redC = (float*)&As[0][0][0];
    if (kg == 1) {
        #pragma unroll
        for (int fm = 0; fm < 2; fm++)
            #pragma unroll
            for (int fn = 0; fn < 2; fn++)
                #pragma unroll
                for (int r4 = 0; r4 < 4; r4++) {
                    int rl = wm * 32 + fm * 16 + (lane >> 4) * 4 + r4;
                    int cl = wn * 32 + fn * 16 + (lane & 15);
                    redC[rl * 64 + cl] = acc[fm][fn][r4];
                }
    }
    __syncthreads();

    if (kg == 0) {
        float s[2] = {0.f, 0.f}, s2[2] = {0.f, 0.f};
        #pragma unroll
        for (int fm = 0; fm < 2; fm++) {
            #pragma unroll
            for (int fn = 0; fn < 2; fn++) {
                #pragma unroll
                for (int r4 = 0; r4 < 4; r4++) {
                    int rl = wm * 32 + fm * 16 + (lane >> 4) * 4 + r4;
                    int cl = wn * 32 + fn * 16 + (lane & 15);
                    int grow = row0 + rl;
                    if (grow < M) {
                        float vv = acc[fm][fn][r4] + redC[rl * 64 + cl];
                        C[(long long)grow * ldc + col0 + cl] = vv;
                        s[fn] += vv; s2[fn] += vv * vv;
                    }
                }
            }
        }
        #pragma unroll
        for (int off = 16; off < 64; off <<= 1) {
            s[0] += __shfl_xor(s[0], off);  s2[0] += __shfl_xor(s2[0], off);
            s[1] += __shfl_xor(s[1], off);  s2[1] += __shfl_xor(s2[1], off);
        }
        if (lane < 16) {
            red[wq][0][lane][0] = s[0]; red[wq][0][lane][1] = s2[0];
            red[wq][1][lane][0] = s[1]; red[wq][1][lane][1] = s2[1];
        }
    }
    __syncthreads();
    if (tid < 128) {
        int col = tid >> 1, which = tid & 1;
        int wn2 = (col >> 5) & 1, fn2 = (col >> 4) & 1, c16 = col & 15;
        float vv = red[wn2][fn2][c16][which] + red[2 + wn2][fn2][c16][which];
        partial[((long long)(bz * 8 + bx) * 2 + which) * 256 + by * 64 + col] = vv;
    }
}

// ============ K3: qkv GEMM [3360x256]*[768x256]^T -> bf16, BN-final recomputed inline ============
__global__ __launch_bounds__(256) void gemm_qkv(
    const float* __restrict__ xraw, const __hip_bfloat16* __restrict__ Bt,
    const float* __restrict__ partial, const float* __restrict__ gamma,
    const float* __restrict__ beta, float* __restrict__ ssbuf,
    __hip_bfloat16* __restrict__ qkv16)
{
    const int M = 3360, K = 256;
    __shared__ short As[2][4096];
    __shared__ short Bs[2][4096];
    __shared__ float ssl[512];
    int tid = threadIdx.x, lane = tid & 63, w = tid >> 6;
    int wm = w >> 1, wn = w & 1;
    int row0 = blockIdx.x * 64, col0 = blockIdx.y * 64;

    {
        float s = 0.f, s2 = 0.f;
        #pragma unroll 8
        for (int bb = 0; bb < 56; bb++) {
            s  += partial[bb * 512 + tid];
            s2 += partial[bb * 512 + 256 + tid];
        }
        float mu = s * (1.f / NTOK);
        float var = s2 * (1.f / NTOK) - mu * mu;
        float rsig = rsqrtf(var + 1e-5f);
        float sc = gamma[tid] * rsig;
        float sh = beta[tid] - mu * sc;
        ssl[tid] = sc;
        ssl[256 + tid] = sh;
        if (blockIdx.x == 0 && blockIdx.y == 0) {
            ssbuf[tid] = sc;
            ssbuf[256 + tid] = sh;
        }
    }
    __syncthreads();

    f32x4 acc[2][2] = {};

    auto stageB = [&](int buf, int k0) {
        int cc = lane & 7;
        #pragma unroll
        for (int i = 0; i < 2; i++) {
            int r = w * 16 + i * 8 + (lane >> 3);
            const char* gb = (const char*)Bt + (((long long)(col0 + r) * K + k0) << 1) + ((cc ^ (r & 7)) << 4);
            gl_lds16(gb, (char*)&Bs[buf][0] + (w * 16 + i * 8) * 128);
        }
    };
    auto stageA = [&](int buf, int k0) {
        #pragma unroll
        for (int i = 0; i < 2; i++) {
            int id = tid + i * 256;
            int r = id >> 3, c8 = id & 7;
            int grow = row0 + r; if (grow >= M) grow = M - 1;
            const float* src = xraw + (long long)grow * 256 + k0 + c8 * 8;
            float4 v0 = *(const float4*)src;
            float4 v1 = *(const float4*)(src + 4);
            int kb = k0 + c8 * 8;
            float vv[8] = {v0.x, v0.y, v0.z, v0.w, v1.x, v1.y, v1.z, v1.w};
            short8 o;
            #pragma unroll
            for (int j = 0; j < 8; j++) {
                float tv = vv[j] * ssl[kb + j] + ssl[256 + kb + j];
                union { __hip_bfloat16 h; short s; } u; u.h = __float2bfloat16(tv);
                o[j] = u.s;
            }
            *(short8*)((char*)&As[buf][0] + r * 128 + ((c8 ^ (r & 7)) << 4)) = o;
        }
    };

    stageA(0, 0); stageB(0, 0);
    __syncthreads();
    for (int t = 0; t < 4; t++) {
        int cur = t & 1;
        if (t + 1 < 4) { stageA(cur ^ 1, (t + 1) << 6); stageB(cur ^ 1, (t + 1) << 6); }
        #pragma unroll
        for (int ks = 0; ks < 2; ks++) {
            bf16x8 af[2], bfv[2];
            #pragma unroll
            for (int f = 0; f < 2; f++) {
                int r = wm * 32 + f * 16 + (lane & 15);
                int ca = (ks * 4 + (lane >> 4)) ^ (r & 7);
                af[f] = *(const bf16x8*)((const char*)&As[cur][0] + r * 128 + (ca << 4));
                int rb = wn * 32 + f * 16 + (lane & 15);
                int cb = (ks * 4 + (lane >> 4)) ^ (rb & 7);
                bfv[f] = *(const bf16x8*)((const char*)&Bs[cur][0] + rb * 128 + (cb << 4));
            }
            #pragma unroll
            for (int fm = 0; fm < 2; fm++)
                #pragma unroll
                for (int fn = 0; fn < 2; fn++)
                    acc[fm][fn] = __builtin_amdgcn_mfma_f32_16x16x32_bf16(
                        af[fm], bfv[fn], acc[fm][fn], 0, 0, 0);
        }
        __syncthreads();
    }
    #pragma unroll
    for (int fm = 0; fm < 2; fm++)
        #pragma unroll
        for (int fn = 0; fn < 2; fn++)
            #pragma unroll
            for (int r4 = 0; r4 < 4; r4++) {
                int grow = row0 + wm * 32 + fm * 16 + (lane >> 4) * 4 + r4;
                int gcol = col0 + wn * 32 + fn * 16 + (lane & 15);
                if (grow < M)
                    qkv16[(long long)grow * 768 + gcol] = __float2bfloat16(acc[fm][fn][r4]);
            }
}

// ============ K4: attention + proj(swapped operands) + residual + DIRECT transposed out ============
__global__ __launch_bounds__(256) void attnproj(const __hip_bfloat16* __restrict__ qkv16,
                                                const __hip_bfloat16* __restrict__ wproj16,
                                                const float* __restrict__ xraw,
                                                const float* __restrict__ ssb,
                                                float* __restrict__ outp) {
    __shared__ __align__(16) char sm[40736];
    float* qkvs  = (float*)sm;                        // [7*LDQ] f32 = 21728 B
    short* ao_s  = (short*)(sm + 21728);              // [16*256] bf16 = 8192 B
    float* res_s = (float*)(sm + 29920);              // [7*257] f32 = 7196 B (BN applied)
    float (*as_)[49] = (float(*)[49])(sm + 37120);    // 1568 B

    int tid = threadIdx.x, lane = tid & 63, w = tid >> 6;
    int token0 = blockIdx.x * 7;

    // phase 1: qkv rows -> padded f32 LDS; BN(residual) rows -> res_s (coalesced)
    const short* src = (const short*)qkv16 + (long long)token0 * 768;
    for (int c = tid; c < 672; c += 256) {
        int r = c / 96, c8 = (c % 96) * 8;
        short8 v = *(const short8*)(src + r * 768 + c8);
        float4 f0, f1;
        f0.x = bf2f(v[0]); f0.y = bf2f(v[1]); f0.z = bf2f(v[2]); f0.w = bf2f(v[3]);
        f1.x = bf2f(v[4]); f1.y = bf2f(v[5]); f1.z = bf2f(v[6]); f1.w = bf2f(v[7]);
        *(float4*)&qkvs[r * LDQ + c8] = f0;
        *(float4*)&qkvs[r * LDQ + c8 + 4] = f1;
    }
    {
        float sc = ssb[tid], sh = ssb[256 + tid];
        #pragma unroll
        for (int r = 0; r < 7; r++)
            res_s[r * 257 + tid] = xraw[(long long)(token0 + r) * 256 + tid] * sc + sh;
    }
    __syncthreads();

    // phase 2: attention scores (softmax over HEADS)
    for (int t = tid; t < 392; t += 256) {
        int h = t / 49, ij = t % 49, i = ij / 7, j = ij % 7;
        const float* qp = qkvs + i * LDQ + h * 32;
        const float* kp = qkvs + j * LDQ + 256 + h * 32;
        float acc = 0.f;
        #pragma unroll
        for (int d = 0; d < 32; d++) acc += qp[d] * kp[d];
        as_[h][ij] = acc * 0.17677669529663689f;
    }
    __syncthreads();
    // phase 3: softmax over heads
    if (tid < 49) {
        float m = -INFINITY;
        #pragma unroll
        for (int h = 0; h < 8; h++) m = fmaxf(m, as_[h][tid]);
        float e[8], sum = 0.f;
        #pragma unroll
        for (int h = 0; h < 8; h++) { e[h] = __expf(as_[h][tid] - m); sum += e[h]; }
        float inv = 1.f / sum;
        #pragma unroll
        for (int h = 0; h < 8; h++) as_[h][tid] = e[h] * inv;
    }
    __syncthreads();
    // phase 4: ao rows (pads zero), XOR-swizzled bf16 store
    #pragma unroll
    for (int tl = 0; tl < 16; tl++) {
        int col = tid;
        float acc = 0.f;
        if (tl < 7) {
            int h = col >> 5;
            const float* ap = &as_[h][tl * 7];
            const float* vp = qkvs + 512 + col;
            #pragma unroll
            for (int j = 0; j < 7; j++) acc += ap[j] * vp[j * LDQ];
        }
        int c16 = col >> 3;
        union { __hip_bfloat16 h2; short s2; } u; u.h2 = __float2bfloat16(acc);
        ao_s[tl * 256 + ((c16 ^ (tl & 7)) << 3) + (col & 7)] = u.s2;
    }
    __syncthreads();
    // phase 5: proj MFMA, swapped operands: C[o][token] -> direct transposed write
    f32x4 pacc[4] = {};
    int n0 = w * 64;
    #pragma unroll
    for (int k0 = 0; k0 < 256; k0 += 32) {
        int kk = k0 + (lane >> 4) * 8;
        int rowb = lane & 15;
        int c16b = kk >> 3;
        bf16x8 bfr = *(const bf16x8*)(const void*)&ao_s[rowb * 256 + ((c16b ^ (rowb & 7)) << 3)];
        #pragma unroll
        for (int fo = 0; fo < 4; fo++) {
            int o = n0 + fo * 16 + (lane & 15);
            bf16x8 afr = *(const bf16x8*)(const void*)((const short*)wproj16 + o * 256 + kk);
            pacc[fo] = __builtin_amdgcn_mfma_f32_16x16x32_bf16(afr, bfr, pacc[fo], 0, 0, 0);
        }
    }
    int tk = lane & 15;
    if (tk < 7) {
        int n = token0 / 210, rem0 = token0 % 210;   // 210 = 30*7: never straddles n
        #pragma unroll
        for (int fo = 0; fo < 4; fo++)
            #pragma unroll
            for (int r4 = 0; r4 < 4; r4++) {
                int o = n0 + fo * 16 + (lane >> 4) * 4 + r4;
                outp[((long long)(n * 256 + o)) * 210 + rem0 + tk] =
                    pacc[fo][r4] + res_s[tk * 257 + o];
            }
    }
}

extern "C" void kernel_launch(void* const* d_in, const int* in_sizes, int n_in,
                              void* d_out, int out_size, void* d_ws, size_t ws_size,
                              hipStream_t stream) {
    const float* sil   = (const float*)d_in[0];
    const float* pose  = (const float*)d_in[1];
    const float* fcbin = (const float*)d_in[2];
    const float* gamma = (const float*)d_in[3];
    const float* beta  = (const float*)d_in[4];
    const float* wqkv  = (const float*)d_in[5];
    const float* wproj = (const float*)d_in[6];
    const int*   minidx= (const int*)d_in[7];
    float* out = (float*)d_out;

    float* ws = (float*)d_ws;
    __hip_bfloat16* fuse16   = (__hip_bfloat16*)ws;             // 5,160,960 bf16
    float* xraw    = ws + 2580480;                              // 860,160 f32 (ldc=1792 view)
    float* partial = ws + 3440640;                              // 28,672
    float* ssbuf   = ws + 3469312;                              // 512
    __hip_bfloat16* wqkv16   = (__hip_bfloat16*)(ws + 3469824); // 196,608 bf16
    __hip_bfloat16* wproj16  = (__hip_bfloat16*)(ws + 3568128); // 65,536 bf16
    __hip_bfloat16* fcbinT16 = (__hip_bfloat16*)(ws + 3600896); // 2,752,512 bf16
    __hip_bfloat16* qkv16    = (__hip_bfloat16*)(ws + 4977152); // 2,580,480 bf16

    prep<<<7216, 256, 0, stream>>>(sil, minidx, wqkv, wproj, fcbin, pose,
                                   fuse16, wqkv16, wproj16, fcbinT16);
    gemm_fc<<<224, 512, 0, stream>>>(fuse16, fcbinT16, xraw, partial);
    gemm_qkv<<<dim3(53, 12), 256, 0, stream>>>(xraw, wqkv16, partial, gamma, beta, ssbuf, qkv16);
    attnproj<<<480, 256, 0, stream>>>(qkv16, wproj16, xraw, ssbuf, out);
}